// Round 7
// baseline (534.179 us; speedup 1.0000x reference)
//
#include <hip/hip_runtime.h>

#define NEG_SLOPE 0.2f

typedef __bf16 bf16x8 __attribute__((ext_vector_type(8)));
typedef float floatx4 __attribute__((ext_vector_type(4)));
typedef unsigned short ushortx4 __attribute__((ext_vector_type(4)));
typedef unsigned short ushortx8 __attribute__((ext_vector_type(8)));

__device__ __forceinline__ float eluf(float x) { return x > 0.f ? x : __expf(x) - 1.f; }
__device__ __forceinline__ float lrelu(float x) { return x > 0.f ? x : NEG_SLOPE * x; }

__device__ __forceinline__ unsigned short f2bf(float f) {
    unsigned u = __float_as_uint(f);
    u += 0x7FFFu + ((u >> 16) & 1u);           // round-to-nearest-even
    return (unsigned short)(u >> 16);
}
__device__ __forceinline__ float bf2f(unsigned short h) {
    return __uint_as_float(((unsigned)h) << 16);
}

// ================= merged prep: count | x->bf16 | W1^T | W2^T | U = W1·a =================
__global__ __launch_bounds__(256) void prep_kernel(
        const int* __restrict__ ei, int E, int N, int* __restrict__ counts,
        const float* __restrict__ x, unsigned short* __restrict__ xb,
        const float* __restrict__ W1, unsigned short* __restrict__ w1t,
        const float* __restrict__ W2, unsigned short* __restrict__ w2t,
        const float* __restrict__ as1, const float* __restrict__ ad1, float* __restrict__ U) {
    __shared__ float tile[32][33];
    int b = blockIdx.x;
    int t = threadIdx.x;
    int Et = E + N;
    int nA = (Et + 255) >> 8;
    int nB = (N * 96 + 255) >> 8;           // N*384/4 float4 groups
    if (b < nA) {
        // ---- degree count ----
        int i = b * 256 + t;
        if (i < Et) {
            int d = (i < E) ? ei[E + i] : (i - E);
            atomicAdd(&counts[d], 1);
        }
    } else if (b < nA + nB) {
        // ---- x fp32 -> bf16 ----
        int i = (b - nA) * 256 + t;
        if (i < N * 96) {
            float4 v = ((const float4*)x)[i];
            ushortx4 o;
            o[0] = f2bf(v.x); o[1] = f2bf(v.y); o[2] = f2bf(v.z); o[3] = f2bf(v.w);
            *(ushortx4*)(xb + (size_t)i * 4) = o;
        }
    } else if (b < nA + nB + 384) {
        // ---- W1 [384][1024] -> w1t [1024][384] bf16 ----
        int idx = b - nA - nB;
        int n0 = (idx & 31) * 32, k0 = (idx >> 5) * 32;
        int tx = t & 31, ty = t >> 5;
        #pragma unroll
        for (int i = 0; i < 32; i += 8)
            tile[ty + i][tx] = W1[(size_t)(k0 + ty + i) * 1024 + n0 + tx];
        __syncthreads();
        #pragma unroll
        for (int i = 0; i < 32; i += 8)
            w1t[(size_t)(n0 + ty + i) * 384 + k0 + tx] = f2bf(tile[tx][ty + i]);
    } else if (b < nA + nB + 384 + 256) {
        // ---- W2 [1024][256] -> w2t [256][1024] bf16 ----
        int idx = b - nA - nB - 384;
        int n0 = (idx & 7) * 32, k0 = (idx >> 3) * 32;
        int tx = t & 31, ty = t >> 5;
        #pragma unroll
        for (int i = 0; i < 32; i += 8)
            tile[ty + i][tx] = W2[(size_t)(k0 + ty + i) * 256 + n0 + tx];
        __syncthreads();
        #pragma unroll
        for (int i = 0; i < 32; i += 8)
            w2t[(size_t)(n0 + ty + i) * 1024 + k0 + tx] = f2bf(tile[tx][ty + i]);
    } else {
        // ---- U[8][384]: U[r][k] = sum_c W1[k][h*256+c] * a[h][c], h=r&3, a = src(r<4)/dst ----
        int idx = b - nA - nB - 384 - 256;
        int k = idx * 4 + (t >> 6);
        int lane = t & 63;
        #pragma unroll
        for (int r = 0; r < 8; r++) {
            int h = r & 3;
            const float* a = (r < 4 ? as1 : ad1) + h * 256 + lane * 4;
            const float* w = W1 + (size_t)k * 1024 + h * 256 + lane * 4;
            float4 wv = *(const float4*)w;
            float4 av = *(const float4*)a;
            float p = wv.x * av.x + wv.y * av.y + wv.z * av.z + wv.w * av.w;
            #pragma unroll
            for (int off = 32; off; off >>= 1) p += __shfl_xor(p, off);
            if (lane == 0) U[r * 384 + k] = p;
        }
    }
}

// single 1024-thread block; wave-shuffle scan
__global__ void scan_kernel(int* __restrict__ counts_cursor, int* __restrict__ row_ptr, int N) {
    __shared__ int s_wsum[16];
    __shared__ int s_carry;
    int t = threadIdx.x;
    int lane = t & 63, wid = t >> 6;
    if (t == 0) { s_carry = 0; row_ptr[0] = 0; }
    __syncthreads();
    for (int start = 0; start < N; start += 1024) {
        int i = start + t;
        int v = (i < N) ? counts_cursor[i] : 0;
        int s = v;
        #pragma unroll
        for (int d = 1; d < 64; d <<= 1) {
            int u = __shfl_up(s, d);
            if (lane >= d) s += u;
        }
        if (lane == 63) s_wsum[wid] = s;
        __syncthreads();
        if (wid == 0) {
            int w = (lane < 16) ? s_wsum[lane] : 0;
            #pragma unroll
            for (int d = 1; d < 16; d <<= 1) {
                int u = __shfl_up(w, d);
                if (lane >= d) w += u;
            }
            if (lane < 16) s_wsum[lane] = w;
        }
        __syncthreads();
        int incl = s + (wid ? s_wsum[wid - 1] : 0) + s_carry;
        if (i < N) { row_ptr[i + 1] = incl; counts_cursor[i] = incl - v; }
        __syncthreads();
        if (t == 0) s_carry += s_wsum[15];
        __syncthreads();
    }
}

__global__ void fill_kernel(const int* __restrict__ ei, int E, int N,
                            int* __restrict__ cursor, int* __restrict__ col) {
    int i = blockIdx.x * blockDim.x + threadIdx.x;
    int Et = E + N;
    if (i >= Et) return;
    int s, d;
    if (i < E) { s = ei[i]; d = ei[E + i]; } else { s = d = i - E; }
    int pos = atomicAdd(&cursor[d], 1);
    col[pos] = s;
}

// ---------------- logits via U: ss1[n][h]=x[n]·U[h], sd1[n][h]=x[n]·U[4+h] ----------------
// wave/node; half 0 -> src rows (U[0..3]), half 1 -> dst rows (U[4..7]); 32 lanes × 12 ch.
__global__ void sU_kernel(const unsigned short* __restrict__ xb, const float* __restrict__ U,
                          float* __restrict__ ss1, float* __restrict__ sd1, int N) {
    int wid = (blockIdx.x * blockDim.x + threadIdx.x) >> 6;
    int lane = threadIdx.x & 63;
    if (wid >= N) return;
    int half = lane >> 5, l32 = lane & 31;
    int c0 = l32 * 12;
    const unsigned short* row = xb + (size_t)wid * 384 + c0;
    ushortx8 v8 = *(const ushortx8*)row;
    ushortx4 v4 = *(const ushortx4*)(row + 8);
    float xv[12];
    #pragma unroll
    for (int j = 0; j < 8; j++) xv[j] = bf2f(v8[j]);
    #pragma unroll
    for (int j = 0; j < 4; j++) xv[8 + j] = bf2f(v4[j]);
    float p[4];
    #pragma unroll
    for (int r = 0; r < 4; r++) {
        const float* u = U + (half * 4 + r) * 384 + c0;
        float s = 0.f;
        #pragma unroll
        for (int j = 0; j < 12; j++) s += xv[j] * u[j];
        #pragma unroll
        for (int off = 16; off; off >>= 1) s += __shfl_xor(s, off);
        p[r] = s;
    }
    if (l32 == 0) {
        float* dst = half ? (sd1 + wid * 4) : (ss1 + wid * 4);
        dst[0] = p[0]; dst[1] = p[1]; dst[2] = p[2]; dst[3] = p[3];
    }
}

// ---------------- per-node attention logits, layer 2 (H=1, C=256), bf16 h2 ----------------
__global__ void s2_kernel(const unsigned short* __restrict__ h2b, const float* __restrict__ a_src,
                          const float* __restrict__ a_dst, float* __restrict__ ssrc,
                          float* __restrict__ sdst, int N) {
    int wid = (blockIdx.x * blockDim.x + threadIdx.x) >> 6;
    int lane = threadIdx.x & 63;
    if (wid >= N) return;
    ushortx4 v = *(const ushortx4*)(h2b + (size_t)wid * 256 + lane * 4);
    float4 a = ((const float4*)a_src)[lane];
    float4 d = ((const float4*)a_dst)[lane];
    float v0 = bf2f(v[0]), v1 = bf2f(v[1]), v2 = bf2f(v[2]), v3 = bf2f(v[3]);
    float s = v0 * a.x + v1 * a.y + v2 * a.z + v3 * a.w;
    float t = v0 * d.x + v1 * d.y + v2 * d.z + v3 * d.w;
    for (int off = 32; off; off >>= 1) { s += __shfl_xor(s, off); t += __shfl_xor(t, off); }
    if (lane == 0) { ssrc[wid] = s; sdst[wid] = t; }
}

// ---------------- per-edge softmax weights, layer 1 (H=4) ----------------
__global__ __launch_bounds__(256) void alpha1_kernel(const float* __restrict__ ssrc,
        const float* __restrict__ sdst, const int* __restrict__ row_ptr,
        const int* __restrict__ col, float* __restrict__ wx, float* __restrict__ den, int N) {
    int wid = (blockIdx.x * blockDim.x + threadIdx.x) >> 6;
    int lane = threadIdx.x & 63;
    if (wid >= N) return;
    int base = row_ptr[wid];
    int deg = row_ptr[wid + 1] - base;
    float sd0 = sdst[wid * 4 + 0], sd1 = sdst[wid * 4 + 1];
    float sd2 = sdst[wid * 4 + 2], sd3 = sdst[wid * 4 + 3];
    float m0 = -1e30f, m1 = -1e30f, m2 = -1e30f, m3 = -1e30f;
    for (int i = lane; i < deg; i += 64) {
        int s = col[base + i];
        const float* sp = ssrc + s * 4;
        m0 = fmaxf(m0, lrelu(sp[0] + sd0));
        m1 = fmaxf(m1, lrelu(sp[1] + sd1));
        m2 = fmaxf(m2, lrelu(sp[2] + sd2));
        m3 = fmaxf(m3, lrelu(sp[3] + sd3));
    }
    #pragma unroll
    for (int off = 32; off; off >>= 1) {
        m0 = fmaxf(m0, __shfl_xor(m0, off));
        m1 = fmaxf(m1, __shfl_xor(m1, off));
        m2 = fmaxf(m2, __shfl_xor(m2, off));
        m3 = fmaxf(m3, __shfl_xor(m3, off));
    }
    float d0 = 0.f, d1 = 0.f, d2 = 0.f, d3 = 0.f;
    for (int i = lane; i < deg; i += 64) {
        int s = col[base + i];
        const float* sp = ssrc + s * 4;
        float4 w4;
        w4.x = __expf(lrelu(sp[0] + sd0) - m0); d0 += w4.x;
        w4.y = __expf(lrelu(sp[1] + sd1) - m1); d1 += w4.y;
        w4.z = __expf(lrelu(sp[2] + sd2) - m2); d2 += w4.z;
        w4.w = __expf(lrelu(sp[3] + sd3) - m3); d3 += w4.w;
        *(float4*)(wx + (size_t)(base + i) * 4) = w4;
    }
    #pragma unroll
    for (int off = 32; off; off >>= 1) {
        d0 += __shfl_xor(d0, off);
        d1 += __shfl_xor(d1, off);
        d2 += __shfl_xor(d2, off);
        d3 += __shfl_xor(d3, off);
    }
    if (lane == 0) {
        den[wid * 4 + 0] = d0; den[wid * 4 + 1] = d1;
        den[wid * 4 + 2] = d2; den[wid * 4 + 3] = d3;
    }
}

// ---------------- per-edge softmax weights, layer 2 (H=1) ----------------
__global__ __launch_bounds__(256) void alpha2_kernel(const float* __restrict__ ssrc,
        const float* __restrict__ sdst, const int* __restrict__ row_ptr,
        const int* __restrict__ col, float* __restrict__ wx, float* __restrict__ den, int N) {
    int wid = (blockIdx.x * blockDim.x + threadIdx.x) >> 6;
    int lane = threadIdx.x & 63;
    if (wid >= N) return;
    int base = row_ptr[wid];
    int deg = row_ptr[wid + 1] - base;
    float sd = sdst[wid];
    float m = -1e30f;
    for (int i = lane; i < deg; i += 64) {
        int s = col[base + i];
        m = fmaxf(m, lrelu(ssrc[s] + sd));
    }
    #pragma unroll
    for (int off = 32; off; off >>= 1) m = fmaxf(m, __shfl_xor(m, off));
    float d = 0.f;
    for (int i = lane; i < deg; i += 64) {
        int s = col[base + i];
        float x = __expf(lrelu(ssrc[s] + sd) - m);
        d += x;
        wx[base + i] = x;
    }
    #pragma unroll
    for (int off = 32; off; off >>= 1) d += __shfl_xor(d, off);
    if (lane == 0) den[wid] = d;
}

// ---------------- aggx: per-head weighted aggregation of x rows (384 ch) ----------------
// wave/dst; half h=lane>>5 processes edges i = h, h+2, ...; lane covers 12 channels.
// output aggxn[n][4][384] bf16, already normalized by 1/den.
__global__ __launch_bounds__(256) void aggx_kernel(const unsigned short* __restrict__ xb,
        const float* __restrict__ wx, const float* __restrict__ den,
        const int* __restrict__ row_ptr, const int* __restrict__ col,
        unsigned short* __restrict__ aggxn, int N) {
    int wid = (blockIdx.x * blockDim.x + threadIdx.x) >> 6;
    int lane = threadIdx.x & 63;
    if (wid >= N) return;
    int base = row_ptr[wid];
    int deg = row_ptr[wid + 1] - base;
    int half = lane >> 5, l32 = lane & 31;
    int c0 = l32 * 12;
    float acc[4][12] = {};
    for (int i = half; i < deg; i += 2) {
        int e = base + i;
        int s = col[e];
        float4 w4 = *(const float4*)(wx + (size_t)e * 4);
        const unsigned short* row = xb + (size_t)s * 384 + c0;
        ushortx8 v8 = *(const ushortx8*)row;
        ushortx4 v4 = *(const ushortx4*)(row + 8);
        float xv[12];
        #pragma unroll
        for (int j = 0; j < 8; j++) xv[j] = bf2f(v8[j]);
        #pragma unroll
        for (int j = 0; j < 4; j++) xv[8 + j] = bf2f(v4[j]);
        #pragma unroll
        for (int j = 0; j < 12; j++) {
            acc[0][j] += w4.x * xv[j];
            acc[1][j] += w4.y * xv[j];
            acc[2][j] += w4.z * xv[j];
            acc[3][j] += w4.w * xv[j];
        }
    }
    // combine the two halves (same channels at lane ^ 32)
    #pragma unroll
    for (int h = 0; h < 4; h++)
        #pragma unroll
        for (int j = 0; j < 12; j++)
            acc[h][j] += __shfl_xor(acc[h][j], 32);
    // each half writes 2 heads
    #pragma unroll
    for (int hh = 0; hh < 2; hh++) {
        int h = half * 2 + hh;
        float inv = 1.f / (den[wid * 4 + h] + 1e-16f);
        ushortx8 o8; ushortx4 o4;
        #pragma unroll
        for (int j = 0; j < 8; j++) o8[j] = f2bf(acc[h][j] * inv);
        #pragma unroll
        for (int j = 0; j < 4; j++) o4[j] = f2bf(acc[h][8 + j] * inv);
        unsigned short* op = aggxn + (size_t)wid * 1536 + h * 384 + c0;
        *(ushortx8*)op = o8;
        *(ushortx4*)(op + 8) = o4;
    }
}

#define LDK 40  // 32 + 8 pad (shorts) -> 80 B row stride, 2-way (free) frag-read conflicts

// ---------------- layer-1 head-GEMM: h1e = elu(aggxn_head @ w1t_cols + b1), bf16 out ----------------
// A = aggxn [M][1536] (head-major), Bt = w1t [1024][384], col tile 128 -> head = col0>>8.
__global__ __launch_bounds__(256) void gemm_l1(const unsigned short* __restrict__ A,
        const unsigned short* __restrict__ Bt, const float* __restrict__ bias,
        unsigned short* __restrict__ Cout, int M) {
    __shared__ unsigned short As[128 * LDK];
    __shared__ unsigned short Bs[128 * LDK];
    int t = threadIdx.x;
    int lane = t & 63, wave = t >> 6;
    int wm = (wave >> 1) * 64, wn = (wave & 1) * 64;
    int q = lane >> 4, l16 = lane & 15;
    int row0 = blockIdx.y * 128, col0 = blockIdx.x * 128;
    int hoff = (col0 >> 8) * 384;
    floatx4 acc[4][4] = {};
    int sg = (t & 7) * 4;
    int sr = t >> 3;
    for (int kt = 0; kt < 384; kt += 32) {
        #pragma unroll
        for (int p = 0; p < 4; p++) {
            int r = sr + p * 32;
            int ga = min(row0 + r, M - 1);
            *(ushortx4*)&As[r * LDK + sg] = *(const ushortx4*)(A + (size_t)ga * 1536 + hoff + kt + sg);
        }
        #pragma unroll
        for (int p = 0; p < 4; p++) {
            int r = sr + p * 32;
            *(ushortx4*)&Bs[r * LDK + sg] = *(const ushortx4*)(Bt + (size_t)(col0 + r) * 384 + kt + sg);
        }
        __syncthreads();
        bf16x8 af[4], bfr[4];
        #pragma unroll
        for (int i = 0; i < 4; i++)
            af[i] = *(const bf16x8*)&As[(wm + i * 16 + l16) * LDK + q * 8];
        #pragma unroll
        for (int j = 0; j < 4; j++)
            bfr[j] = *(const bf16x8*)&Bs[(wn + j * 16 + l16) * LDK + q * 8];
        #pragma unroll
        for (int i = 0; i < 4; i++)
            #pragma unroll
            for (int j = 0; j < 4; j++)
                acc[i][j] = __builtin_amdgcn_mfma_f32_16x16x32_bf16(af[i], bfr[j], acc[i][j], 0, 0, 0);
        __syncthreads();
    }
    float bj[4];
    #pragma unroll
    for (int j = 0; j < 4; j++) bj[j] = bias[col0 + wn + l16 + j * 16];
    #pragma unroll
    for (int i = 0; i < 4; i++) {
        #pragma unroll
        for (int r = 0; r < 4; r++) {
            int grow = row0 + wm + i * 16 + q * 4 + r;
            if (grow < M) {
                unsigned short* cp = Cout + (size_t)grow * 1024 + col0 + wn + l16;
                #pragma unroll
                for (int j = 0; j < 4; j++) cp[j * 16] = f2bf(eluf(acc[i][j][r] + bj[j]));
            }
        }
    }
}

// ---------------- bf16 MFMA GEMM (layer 2): C = A @ Bt^T, bf16 out ----------------
template <int TN>
__global__ __launch_bounds__(256) void gemm_1t(const unsigned short* __restrict__ A,
        const unsigned short* __restrict__ Bt, unsigned short* __restrict__ Cout,
        int M, int N, int K) {
    constexpr int JN = TN / 32;
    __shared__ unsigned short As[128 * LDK];
    __shared__ unsigned short Bs[TN * LDK];
    int t = threadIdx.x;
    int lane = t & 63, wave = t >> 6;
    int wm = (wave >> 1) * 64, wn = (wave & 1) * (TN / 2);
    int q = lane >> 4, l16 = lane & 15;
    int row0 = blockIdx.y * 128, col0 = blockIdx.x * TN;
    floatx4 acc[4][JN] = {};
    int sg = (t & 7) * 4;
    int sr = t >> 3;
    for (int kt = 0; kt < K; kt += 32) {
        #pragma unroll
        for (int p = 0; p < 4; p++) {
            int r = sr + p * 32;
            int ga = min(row0 + r, M - 1);
            *(ushortx4*)&As[r * LDK + sg] = *(const ushortx4*)(A + (size_t)ga * K + kt + sg);
        }
        #pragma unroll
        for (int p = 0; p < TN / 32; p++) {
            int r = sr + p * 32;
            *(ushortx4*)&Bs[r * LDK + sg] = *(const ushortx4*)(Bt + (size_t)(col0 + r) * K + kt + sg);
        }
        __syncthreads();
        bf16x8 af[4], bfr[JN];
        #pragma unroll
        for (int i = 0; i < 4; i++)
            af[i] = *(const bf16x8*)&As[(wm + i * 16 + l16) * LDK + q * 8];
        #pragma unroll
        for (int j = 0; j < JN; j++)
            bfr[j] = *(const bf16x8*)&Bs[(wn + j * 16 + l16) * LDK + q * 8];
        #pragma unroll
        for (int i = 0; i < 4; i++)
            #pragma unroll
            for (int j = 0; j < JN; j++)
                acc[i][j] = __builtin_amdgcn_mfma_f32_16x16x32_bf16(af[i], bfr[j], acc[i][j], 0, 0, 0);
        __syncthreads();
    }
    #pragma unroll
    for (int i = 0; i < 4; i++) {
        #pragma unroll
        for (int r = 0; r < 4; r++) {
            int grow = row0 + wm + i * 16 + q * 4 + r;
            if (grow < M) {
                unsigned short* cp = Cout + (size_t)grow * N + col0 + wn + l16;
                #pragma unroll
                for (int j = 0; j < JN; j++) cp[j * 16] = f2bf(acc[i][j][r]);
            }
        }
    }
}

// ---------------- layer-2 aggregation: 2-edge unrolled gather; fp32 out ----------------
__global__ __launch_bounds__(256) void agg2_kernel(const unsigned short* __restrict__ h2b,
        const float* __restrict__ wx, const float* __restrict__ den,
        const int* __restrict__ row_ptr, const int* __restrict__ col,
        const float* __restrict__ bias, float* __restrict__ out, int N) {
    int wid = (blockIdx.x * blockDim.x + threadIdx.x) >> 6;
    int lane = threadIdx.x & 63;
    if (wid >= N) return;
    int base = row_ptr[wid];
    int deg = row_ptr[wid + 1] - base;
    float4 a = {0, 0, 0, 0};
    int c = lane * 4;
    int i = 0;
    for (; i + 1 < deg; i += 2) {
        int s0 = col[base + i], s1 = col[base + i + 1];
        float x0 = wx[base + i], x1 = wx[base + i + 1];
        ushortx4 v0 = *(const ushortx4*)(h2b + (size_t)s0 * 256 + c);
        ushortx4 v1 = *(const ushortx4*)(h2b + (size_t)s1 * 256 + c);
        a.x += x0 * bf2f(v0[0]) + x1 * bf2f(v1[0]);
        a.y += x0 * bf2f(v0[1]) + x1 * bf2f(v1[1]);
        a.z += x0 * bf2f(v0[2]) + x1 * bf2f(v1[2]);
        a.w += x0 * bf2f(v0[3]) + x1 * bf2f(v1[3]);
    }
    if (i < deg) {
        int s0 = col[base + i];
        float x0 = wx[base + i];
        ushortx4 v0 = *(const ushortx4*)(h2b + (size_t)s0 * 256 + c);
        a.x += x0 * bf2f(v0[0]); a.y += x0 * bf2f(v0[1]);
        a.z += x0 * bf2f(v0[2]); a.w += x0 * bf2f(v0[3]);
    }
    float inv = 1.f / (den[wid] + 1e-16f);
    float4 o;
    o.x = eluf(a.x * inv + bias[c + 0]);
    o.y = eluf(a.y * inv + bias[c + 1]);
    o.z = eluf(a.z * inv + bias[c + 2]);
    o.w = eluf(a.w * inv + bias[c + 3]);
    *(float4*)(out + (size_t)wid * 256 + c) = o;
}

// ---------------- merged tail: influence head (8 nodes/block, 2 groups) | mean ----------------
__global__ __launch_bounds__(256) void tail_kernel(const float* __restrict__ h,
        const float* __restrict__ Wp1, const float* __restrict__ bp1,
        const float* __restrict__ Wp2, const float* __restrict__ bp2,
        float* __restrict__ gf, float* __restrict__ infl, int N) {
    int b = blockIdx.x;
    int nInfl = (N + 7) / 8;
    if (b < nInfl) {
        __shared__ float sh[8][256];
        __shared__ float red[8][128];
        int t = threadIdx.x;
        int g = t >> 7, tt = t & 127;
        int nb = b * 8 + g * 4;
        #pragma unroll
        for (int r = 0; r < 4; r++) {
            int n = nb + r;
            if (n < N) {
                sh[g * 4 + r][tt] = h[(size_t)n * 256 + tt];
                sh[g * 4 + r][tt + 128] = h[(size_t)n * 256 + tt + 128];
            }
        }
        __syncthreads();
        float acc0 = bp1[tt], acc1 = acc0, acc2 = acc0, acc3 = acc0;
        for (int k = 0; k < 256; k++) {
            float w = Wp1[k * 128 + tt];
            acc0 += sh[g * 4 + 0][k] * w;
            acc1 += sh[g * 4 + 1][k] * w;
            acc2 += sh[g * 4 + 2][k] * w;
            acc3 += sh[g * 4 + 3][k] * w;
        }
        float w2 = Wp2[tt];
        red[g * 4 + 0][tt] = fmaxf(acc0, 0.f) * w2;
        red[g * 4 + 1][tt] = fmaxf(acc1, 0.f) * w2;
        red[g * 4 + 2][tt] = fmaxf(acc2, 0.f) * w2;
        red[g * 4 + 3][tt] = fmaxf(acc3, 0.f) * w2;
        __syncthreads();
        for (int s = 64; s > 0; s >>= 1) {
            if (tt < s) {
                red[g * 4 + 0][tt] += red[g * 4 + 0][tt + s];
                red[g * 4 + 1][tt] += red[g * 4 + 1][tt + s];
                red[g * 4 + 2][tt] += red[g * 4 + 2][tt + s];
                red[g * 4 + 3][tt] += red[g * 4 + 3][tt + s];
            }
            __syncthreads();
        }
        if (tt < 4) {
            int n = nb + tt;
            if (n < N) {
                float v = red[g * 4 + tt][0] + bp2[0];
                infl[n] = 1.f / (1.f + __expf(-v));
            }
        }
    } else {
        int bb = b - nInfl;            // 0..79
        int c = threadIdx.x;
        int per = (N + 79) / 80;
        int n0 = bb * per;
        int n1 = min(N, n0 + per);
        float acc = 0.f;
        for (int n = n0; n < n1; n++) acc += h[(size_t)n * 256 + c];
        atomicAdd(&gf[c], acc * (1.0f / N));
    }
}

extern "C" void kernel_launch(void* const* d_in, const int* in_sizes, int n_in,
                              void* d_out, int out_size, void* d_ws, size_t ws_size,
                              hipStream_t stream) {
    const float* x   = (const float*)d_in[0];
    const int*   ei  = (const int*)d_in[1];
    const float* W1  = (const float*)d_in[2];
    const float* as1 = (const float*)d_in[3];
    const float* ad1 = (const float*)d_in[4];
    const float* b1  = (const float*)d_in[5];
    const float* W2  = (const float*)d_in[6];
    const float* as2 = (const float*)d_in[7];
    const float* ad2 = (const float*)d_in[8];
    const float* b2  = (const float*)d_in[9];
    const float* Wp1 = (const float*)d_in[10];
    const float* bp1 = (const float*)d_in[11];
    const float* Wp2 = (const float*)d_in[12];
    const float* bp2 = (const float*)d_in[13];

    const int N  = in_sizes[0] / 384;   // 20000
    const int E  = in_sizes[1] / 2;     // 320000
    const int Et = E + N;

    // ---- workspace layout ----
    char* wsp = (char*)d_ws;
    unsigned short* xb    = (unsigned short*)wsp; wsp += (size_t)N * 384  * sizeof(short);
    unsigned short* aggxn = (unsigned short*)wsp; wsp += (size_t)N * 1536 * sizeof(short);
    unsigned short* h1eb  = (unsigned short*)wsp; wsp += (size_t)N * 1024 * sizeof(short);
    unsigned short* h2b   = (unsigned short*)wsp; wsp += (size_t)N * 256  * sizeof(short);
    unsigned short* w1t   = (unsigned short*)wsp; wsp += (size_t)1024 * 384 * sizeof(short);
    unsigned short* w2t   = (unsigned short*)wsp; wsp += (size_t)256 * 1024 * sizeof(short);
    float* U   = (float*)wsp; wsp += (size_t)8 * 384 * sizeof(float);
    float* ss1 = (float*)wsp; wsp += (size_t)N * 4 * sizeof(float);
    float* sd1 = (float*)wsp; wsp += (size_t)N * 4 * sizeof(float);
    float* ss2 = (float*)wsp; wsp += (size_t)N * sizeof(float);
    float* sd2 = (float*)wsp; wsp += (size_t)N * sizeof(float);
    float* den1 = (float*)wsp; wsp += (size_t)N * 4 * sizeof(float);
    float* den2 = (float*)wsp; wsp += (size_t)N * sizeof(float);
    float* wx1  = (float*)wsp; wsp += (size_t)Et * 4 * sizeof(float);
    float* wx2  = (float*)wsp; wsp += (size_t)Et * sizeof(float);
    int* row_ptr = (int*)wsp; wsp += (size_t)(N + 1) * sizeof(int);
    int* cursor  = (int*)wsp; wsp += (size_t)N * sizeof(int);
    int* col     = (int*)wsp;

    float* out_h  = (float*)d_out;             // [N,256]
    float* out_gf = out_h + (size_t)N * 256;   // [256]
    float* out_if = out_gf + 256;              // [N]

    // prep (count + convert + transposes + U) ; cursor must be zeroed first
    hipMemsetAsync(cursor, 0, (size_t)N * sizeof(int), stream);
    int nA = (Et + 255) / 256;
    int nB = (N * 96 + 255) / 256;
    int nPrep = nA + nB + 384 + 256 + 96;
    prep_kernel<<<nPrep, 256, 0, stream>>>(ei, E, N, cursor, x, xb, W1, w1t, W2, w2t, as1, ad1, U);
    scan_kernel<<<1, 1024, 0, stream>>>(cursor, row_ptr, N);
    fill_kernel<<<nA, 256, 0, stream>>>(ei, E, N, cursor, col);

    // layer 1 (h1 never materialized)
    sU_kernel<<<(N + 3) / 4, 256, 0, stream>>>(xb, U, ss1, sd1, N);
    alpha1_kernel<<<(N + 3) / 4, 256, 0, stream>>>(ss1, sd1, row_ptr, col, wx1, den1, N);
    aggx_kernel<<<(N + 3) / 4, 256, 0, stream>>>(xb, wx1, den1, row_ptr, col, aggxn, N);
    gemm_l1<<<dim3(8, (N + 127) / 128), 256, 0, stream>>>(aggxn, w1t, b1, h1eb, N);

    // layer 2
    gemm_1t<64><<<dim3(4, (N + 127) / 128), 256, 0, stream>>>(h1eb, w2t, h2b, N, 256, 1024);
    s2_kernel<<<(N + 3) / 4, 256, 0, stream>>>(h2b, as2, ad2, ss2, sd2, N);
    alpha2_kernel<<<(N + 3) / 4, 256, 0, stream>>>(ss2, sd2, row_ptr, col, wx2, den2, N);
    agg2_kernel<<<(N + 3) / 4, 256, 0, stream>>>(h2b, wx2, den2, row_ptr, col, b2, out_h, N);

    // outputs 2 & 3 (merged)
    hipMemsetAsync(out_gf, 0, 256 * sizeof(float), stream);
    tail_kernel<<<(N + 7) / 8 + 80, 256, 0, stream>>>(out_h, Wp1, bp1, Wp2, bp2, out_gf, out_if, N);
}

// Round 8
// 530.367 us; speedup vs baseline: 1.0072x; 1.0072x over previous
//
#include <hip/hip_runtime.h>

#define NEG_SLOPE 0.2f

typedef __bf16 bf16x8 __attribute__((ext_vector_type(8)));
typedef float floatx4 __attribute__((ext_vector_type(4)));
typedef unsigned short ushortx4 __attribute__((ext_vector_type(4)));
typedef unsigned short ushortx8 __attribute__((ext_vector_type(8)));

__device__ __forceinline__ float eluf(float x) { return x > 0.f ? x : __expf(x) - 1.f; }
__device__ __forceinline__ float lrelu(float x) { return x > 0.f ? x : NEG_SLOPE * x; }

__device__ __forceinline__ unsigned short f2bf(float f) {
    unsigned u = __float_as_uint(f);
    u += 0x7FFFu + ((u >> 16) & 1u);           // round-to-nearest-even
    return (unsigned short)(u >> 16);
}
__device__ __forceinline__ float bf2f(unsigned short h) {
    return __uint_as_float(((unsigned)h) << 16);
}

// ================= merged prep: count | x->bf16 | W1^T | W2^T | U = W1·a =================
__global__ __launch_bounds__(256) void prep_kernel(
        const int* __restrict__ ei, int E, int N, int* __restrict__ counts,
        const float* __restrict__ x, unsigned short* __restrict__ xb,
        const float* __restrict__ W1, unsigned short* __restrict__ w1t,
        const float* __restrict__ W2, unsigned short* __restrict__ w2t,
        const float* __restrict__ as1, const float* __restrict__ ad1, float* __restrict__ U) {
    __shared__ float tile[32][33];
    int b = blockIdx.x;
    int t = threadIdx.x;
    int Et = E + N;
    int nA = (Et + 255) >> 8;
    int nB = (N * 96 + 255) >> 8;           // N*384/4 float4 groups
    if (b < nA) {
        int i = b * 256 + t;
        if (i < Et) {
            int d = (i < E) ? ei[E + i] : (i - E);
            atomicAdd(&counts[d], 1);
        }
    } else if (b < nA + nB) {
        int i = (b - nA) * 256 + t;
        if (i < N * 96) {
            float4 v = ((const float4*)x)[i];
            ushortx4 o;
            o[0] = f2bf(v.x); o[1] = f2bf(v.y); o[2] = f2bf(v.z); o[3] = f2bf(v.w);
            *(ushortx4*)(xb + (size_t)i * 4) = o;
        }
    } else if (b < nA + nB + 384) {
        int idx = b - nA - nB;
        int n0 = (idx & 31) * 32, k0 = (idx >> 5) * 32;
        int tx = t & 31, ty = t >> 5;
        #pragma unroll
        for (int i = 0; i < 32; i += 8)
            tile[ty + i][tx] = W1[(size_t)(k0 + ty + i) * 1024 + n0 + tx];
        __syncthreads();
        #pragma unroll
        for (int i = 0; i < 32; i += 8)
            w1t[(size_t)(n0 + ty + i) * 384 + k0 + tx] = f2bf(tile[tx][ty + i]);
    } else if (b < nA + nB + 384 + 256) {
        int idx = b - nA - nB - 384;
        int n0 = (idx & 7) * 32, k0 = (idx >> 3) * 32;
        int tx = t & 31, ty = t >> 5;
        #pragma unroll
        for (int i = 0; i < 32; i += 8)
            tile[ty + i][tx] = W2[(size_t)(k0 + ty + i) * 256 + n0 + tx];
        __syncthreads();
        #pragma unroll
        for (int i = 0; i < 32; i += 8)
            w2t[(size_t)(n0 + ty + i) * 1024 + k0 + tx] = f2bf(tile[tx][ty + i]);
    } else {
        // U[8][384]: U[r][k] = sum_c W1[k][h*256+c] * a[h][c], h=r&3, a = src(r<4)/dst
        int idx = b - nA - nB - 384 - 256;
        int k = idx * 4 + (t >> 6);
        int lane = t & 63;
        #pragma unroll
        for (int r = 0; r < 8; r++) {
            int h = r & 3;
            const float* a = (r < 4 ? as1 : ad1) + h * 256 + lane * 4;
            const float* w = W1 + (size_t)k * 1024 + h * 256 + lane * 4;
            float4 wv = *(const float4*)w;
            float4 av = *(const float4*)a;
            float p = wv.x * av.x + wv.y * av.y + wv.z * av.z + wv.w * av.w;
            #pragma unroll
            for (int off = 32; off; off >>= 1) p += __shfl_xor(p, off);
            if (lane == 0) U[r * 384 + k] = p;
        }
    }
}

// single 1024-thread block; wave-shuffle scan
__global__ void scan_kernel(int* __restrict__ counts_cursor, int* __restrict__ row_ptr, int N) {
    __shared__ int s_wsum[16];
    __shared__ int s_carry;
    int t = threadIdx.x;
    int lane = t & 63, wid = t >> 6;
    if (t == 0) { s_carry = 0; row_ptr[0] = 0; }
    __syncthreads();
    for (int start = 0; start < N; start += 1024) {
        int i = start + t;
        int v = (i < N) ? counts_cursor[i] : 0;
        int s = v;
        #pragma unroll
        for (int d = 1; d < 64; d <<= 1) {
            int u = __shfl_up(s, d);
            if (lane >= d) s += u;
        }
        if (lane == 63) s_wsum[wid] = s;
        __syncthreads();
        if (wid == 0) {
            int w = (lane < 16) ? s_wsum[lane] : 0;
            #pragma unroll
            for (int d = 1; d < 16; d <<= 1) {
                int u = __shfl_up(w, d);
                if (lane >= d) w += u;
            }
            if (lane < 16) s_wsum[lane] = w;
        }
        __syncthreads();
        int incl = s + (wid ? s_wsum[wid - 1] : 0) + s_carry;
        if (i < N) { row_ptr[i + 1] = incl; counts_cursor[i] = incl - v; }
        __syncthreads();
        if (t == 0) s_carry += s_wsum[15];
        __syncthreads();
    }
}

__global__ void fill_kernel(const int* __restrict__ ei, int E, int N,
                            int* __restrict__ cursor, int* __restrict__ col) {
    int i = blockIdx.x * blockDim.x + threadIdx.x;
    int Et = E + N;
    if (i >= Et) return;
    int s, d;
    if (i < E) { s = ei[i]; d = ei[E + i]; } else { s = d = i - E; }
    int pos = atomicAdd(&cursor[d], 1);
    col[pos] = s;
}

// ---------------- logits via U: ss1[n][h]=x[n]·U[h], sd1[n][h]=x[n]·U[4+h] ----------------
__global__ void sU_kernel(const unsigned short* __restrict__ xb, const float* __restrict__ U,
                          float* __restrict__ ss1, float* __restrict__ sd1, int N) {
    int wid = (blockIdx.x * blockDim.x + threadIdx.x) >> 6;
    int lane = threadIdx.x & 63;
    if (wid >= N) return;
    int half = lane >> 5, l32 = lane & 31;
    int c0 = l32 * 12;
    const unsigned short* row = xb + (size_t)wid * 384 + c0;
    ushortx8 v8 = *(const ushortx8*)row;
    ushortx4 v4 = *(const ushortx4*)(row + 8);
    float xv[12];
    #pragma unroll
    for (int j = 0; j < 8; j++) xv[j] = bf2f(v8[j]);
    #pragma unroll
    for (int j = 0; j < 4; j++) xv[8 + j] = bf2f(v4[j]);
    float p[4];
    #pragma unroll
    for (int r = 0; r < 4; r++) {
        const float* u = U + (half * 4 + r) * 384 + c0;
        float s = 0.f;
        #pragma unroll
        for (int j = 0; j < 12; j++) s += xv[j] * u[j];
        #pragma unroll
        for (int off = 16; off; off >>= 1) s += __shfl_xor(s, off);
        p[r] = s;
    }
    if (l32 == 0) {
        float* dst = half ? (sd1 + wid * 4) : (ss1 + wid * 4);
        dst[0] = p[0]; dst[1] = p[1]; dst[2] = p[2]; dst[3] = p[3];
    }
}

// ---------------- per-node attention logits, layer 2 (H=1, C=256), bf16 h2 ----------------
__global__ void s2_kernel(const unsigned short* __restrict__ h2b, const float* __restrict__ a_src,
                          const float* __restrict__ a_dst, float* __restrict__ ssrc,
                          float* __restrict__ sdst, int N) {
    int wid = (blockIdx.x * blockDim.x + threadIdx.x) >> 6;
    int lane = threadIdx.x & 63;
    if (wid >= N) return;
    ushortx4 v = *(const ushortx4*)(h2b + (size_t)wid * 256 + lane * 4);
    float4 a = ((const float4*)a_src)[lane];
    float4 d = ((const float4*)a_dst)[lane];
    float v0 = bf2f(v[0]), v1 = bf2f(v[1]), v2 = bf2f(v[2]), v3 = bf2f(v[3]);
    float s = v0 * a.x + v1 * a.y + v2 * a.z + v3 * a.w;
    float t = v0 * d.x + v1 * d.y + v2 * d.z + v3 * d.w;
    for (int off = 32; off; off >>= 1) { s += __shfl_xor(s, off); t += __shfl_xor(t, off); }
    if (lane == 0) { ssrc[wid] = s; sdst[wid] = t; }
}

// ---------------- per-edge softmax weights, layer 1 (H=4) ----------------
__global__ __launch_bounds__(256) void alpha1_kernel(const float* __restrict__ ssrc,
        const float* __restrict__ sdst, const int* __restrict__ row_ptr,
        const int* __restrict__ col, float* __restrict__ wx, float* __restrict__ den, int N) {
    int wid = (blockIdx.x * blockDim.x + threadIdx.x) >> 6;
    int lane = threadIdx.x & 63;
    if (wid >= N) return;
    int base = row_ptr[wid];
    int deg = row_ptr[wid + 1] - base;
    float sd0 = sdst[wid * 4 + 0], sd1 = sdst[wid * 4 + 1];
    float sd2 = sdst[wid * 4 + 2], sd3 = sdst[wid * 4 + 3];
    float m0 = -1e30f, m1 = -1e30f, m2 = -1e30f, m3 = -1e30f;
    for (int i = lane; i < deg; i += 64) {
        int s = col[base + i];
        const float* sp = ssrc + s * 4;
        m0 = fmaxf(m0, lrelu(sp[0] + sd0));
        m1 = fmaxf(m1, lrelu(sp[1] + sd1));
        m2 = fmaxf(m2, lrelu(sp[2] + sd2));
        m3 = fmaxf(m3, lrelu(sp[3] + sd3));
    }
    #pragma unroll
    for (int off = 32; off; off >>= 1) {
        m0 = fmaxf(m0, __shfl_xor(m0, off));
        m1 = fmaxf(m1, __shfl_xor(m1, off));
        m2 = fmaxf(m2, __shfl_xor(m2, off));
        m3 = fmaxf(m3, __shfl_xor(m3, off));
    }
    float d0 = 0.f, d1 = 0.f, d2 = 0.f, d3 = 0.f;
    for (int i = lane; i < deg; i += 64) {
        int s = col[base + i];
        const float* sp = ssrc + s * 4;
        float4 w4;
        w4.x = __expf(lrelu(sp[0] + sd0) - m0); d0 += w4.x;
        w4.y = __expf(lrelu(sp[1] + sd1) - m1); d1 += w4.y;
        w4.z = __expf(lrelu(sp[2] + sd2) - m2); d2 += w4.z;
        w4.w = __expf(lrelu(sp[3] + sd3) - m3); d3 += w4.w;
        *(float4*)(wx + (size_t)(base + i) * 4) = w4;
    }
    #pragma unroll
    for (int off = 32; off; off >>= 1) {
        d0 += __shfl_xor(d0, off);
        d1 += __shfl_xor(d1, off);
        d2 += __shfl_xor(d2, off);
        d3 += __shfl_xor(d3, off);
    }
    if (lane == 0) {
        den[wid * 4 + 0] = d0; den[wid * 4 + 1] = d1;
        den[wid * 4 + 2] = d2; den[wid * 4 + 3] = d3;
    }
}

// ---------------- per-edge softmax weights, layer 2 (H=1) ----------------
__global__ __launch_bounds__(256) void alpha2_kernel(const float* __restrict__ ssrc,
        const float* __restrict__ sdst, const int* __restrict__ row_ptr,
        const int* __restrict__ col, float* __restrict__ wx, float* __restrict__ den, int N) {
    int wid = (blockIdx.x * blockDim.x + threadIdx.x) >> 6;
    int lane = threadIdx.x & 63;
    if (wid >= N) return;
    int base = row_ptr[wid];
    int deg = row_ptr[wid + 1] - base;
    float sd = sdst[wid];
    float m = -1e30f;
    for (int i = lane; i < deg; i += 64) {
        int s = col[base + i];
        m = fmaxf(m, lrelu(ssrc[s] + sd));
    }
    #pragma unroll
    for (int off = 32; off; off >>= 1) m = fmaxf(m, __shfl_xor(m, off));
    float d = 0.f;
    for (int i = lane; i < deg; i += 64) {
        int s = col[base + i];
        float x = __expf(lrelu(ssrc[s] + sd) - m);
        d += x;
        wx[base + i] = x;
    }
    #pragma unroll
    for (int off = 32; off; off >>= 1) d += __shfl_xor(d, off);
    if (lane == 0) den[wid] = d;
}

// ---------------- aggx: per-head weighted aggregation of x rows (384 ch) ----------------
// Compute identical to round 7; store path now LDS-staged so the BLOCK writes its 4
// consecutive node-rows (12 KB) fully coalesced (16B/lane contiguous), fixing the 10x
// HBM write amplification seen with 24B-strided partial-line stores.
__global__ __launch_bounds__(256) void aggx_kernel(const unsigned short* __restrict__ xb,
        const float* __restrict__ wx, const float* __restrict__ den,
        const int* __restrict__ row_ptr, const int* __restrict__ col,
        unsigned short* __restrict__ aggxn, int N) {
    __shared__ unsigned short lds[4][1536];
    int t = threadIdx.x;
    int wv = t >> 6;
    int wid = blockIdx.x * 4 + wv;
    int lane = t & 63;
    bool active = wid < N;
    int half = lane >> 5, l32 = lane & 31;
    int c0 = l32 * 12;
    if (active) {
        int base = row_ptr[wid];
        int deg = row_ptr[wid + 1] - base;
        float acc[4][12] = {};
        for (int i = half; i < deg; i += 2) {
            int e = base + i;
            int s = col[e];
            float4 w4 = *(const float4*)(wx + (size_t)e * 4);
            const unsigned short* row = xb + (size_t)s * 384 + c0;
            ushortx8 v8 = *(const ushortx8*)row;
            ushortx4 v4 = *(const ushortx4*)(row + 8);
            float xv[12];
            #pragma unroll
            for (int j = 0; j < 8; j++) xv[j] = bf2f(v8[j]);
            #pragma unroll
            for (int j = 0; j < 4; j++) xv[8 + j] = bf2f(v4[j]);
            #pragma unroll
            for (int j = 0; j < 12; j++) {
                acc[0][j] += w4.x * xv[j];
                acc[1][j] += w4.y * xv[j];
                acc[2][j] += w4.z * xv[j];
                acc[3][j] += w4.w * xv[j];
            }
        }
        // combine the two halves (same channels at lane ^ 32)
        #pragma unroll
        for (int h = 0; h < 4; h++)
            #pragma unroll
            for (int j = 0; j < 12; j++)
                acc[h][j] += __shfl_xor(acc[h][j], 32);
        // each half stages 2 normalized heads into LDS
        #pragma unroll
        for (int hh = 0; hh < 2; hh++) {
            int h = half * 2 + hh;
            float inv = 1.f / (den[wid * 4 + h] + 1e-16f);
            ushortx8 o8; ushortx4 o4;
            #pragma unroll
            for (int j = 0; j < 8; j++) o8[j] = f2bf(acc[h][j] * inv);
            #pragma unroll
            for (int j = 0; j < 4; j++) o4[j] = f2bf(acc[h][8 + j] * inv);
            unsigned short* lp = &lds[wv][h * 384 + c0];
            *(ushortx8*)lp = o8;
            *(ushortx4*)(lp + 8) = o4;
        }
    }
    __syncthreads();
    // block-coalesced store: 3 x (256 threads x 16B) covering 4 consecutive node-rows
    size_t blockBase = (size_t)blockIdx.x * 4 * 1536;
    const unsigned short* lflat = &lds[0][0];
    #pragma unroll
    for (int j = 0; j < 3; j++) {
        int so = j * 2048 + t * 8;            // short offset in [0, 6144)
        int node = blockIdx.x * 4 + so / 1536;
        if (node < N)
            *(ushortx8*)(aggxn + blockBase + so) = *(const ushortx8*)(lflat + so);
    }
}

#define LDK 40  // 32 + 8 pad (shorts) -> 80 B row stride, 2-way (free) frag-read conflicts

// ---------------- layer-1 head-GEMM: h1e = elu(aggxn_head @ w1t_cols + b1), bf16 out ----------------
__global__ __launch_bounds__(256) void gemm_l1(const unsigned short* __restrict__ A,
        const unsigned short* __restrict__ Bt, const float* __restrict__ bias,
        unsigned short* __restrict__ Cout, int M) {
    __shared__ unsigned short As[128 * LDK];
    __shared__ unsigned short Bs[128 * LDK];
    int t = threadIdx.x;
    int lane = t & 63, wave = t >> 6;
    int wm = (wave >> 1) * 64, wn = (wave & 1) * 64;
    int q = lane >> 4, l16 = lane & 15;
    int row0 = blockIdx.y * 128, col0 = blockIdx.x * 128;
    int hoff = (col0 >> 8) * 384;
    floatx4 acc[4][4] = {};
    int sg = (t & 7) * 4;
    int sr = t >> 3;
    for (int kt = 0; kt < 384; kt += 32) {
        #pragma unroll
        for (int p = 0; p < 4; p++) {
            int r = sr + p * 32;
            int ga = min(row0 + r, M - 1);
            *(ushortx4*)&As[r * LDK + sg] = *(const ushortx4*)(A + (size_t)ga * 1536 + hoff + kt + sg);
        }
        #pragma unroll
        for (int p = 0; p < 4; p++) {
            int r = sr + p * 32;
            *(ushortx4*)&Bs[r * LDK + sg] = *(const ushortx4*)(Bt + (size_t)(col0 + r) * 384 + kt + sg);
        }
        __syncthreads();
        bf16x8 af[4], bfr[4];
        #pragma unroll
        for (int i = 0; i < 4; i++)
            af[i] = *(const bf16x8*)&As[(wm + i * 16 + l16) * LDK + q * 8];
        #pragma unroll
        for (int j = 0; j < 4; j++)
            bfr[j] = *(const bf16x8*)&Bs[(wn + j * 16 + l16) * LDK + q * 8];
        #pragma unroll
        for (int i = 0; i < 4; i++)
            #pragma unroll
            for (int j = 0; j < 4; j++)
                acc[i][j] = __builtin_amdgcn_mfma_f32_16x16x32_bf16(af[i], bfr[j], acc[i][j], 0, 0, 0);
        __syncthreads();
    }
    float bj[4];
    #pragma unroll
    for (int j = 0; j < 4; j++) bj[j] = bias[col0 + wn + l16 + j * 16];
    #pragma unroll
    for (int i = 0; i < 4; i++) {
        #pragma unroll
        for (int r = 0; r < 4; r++) {
            int grow = row0 + wm + i * 16 + q * 4 + r;
            if (grow < M) {
                unsigned short* cp = Cout + (size_t)grow * 1024 + col0 + wn + l16;
                #pragma unroll
                for (int j = 0; j < 4; j++) cp[j * 16] = f2bf(eluf(acc[i][j][r] + bj[j]));
            }
        }
    }
}

// ---------------- bf16 MFMA GEMM (layer 2): C = A @ Bt^T, bf16 out ----------------
template <int TN>
__global__ __launch_bounds__(256) void gemm_1t(const unsigned short* __restrict__ A,
        const unsigned short* __restrict__ Bt, unsigned short* __restrict__ Cout,
        int M, int N, int K) {
    constexpr int JN = TN / 32;
    __shared__ unsigned short As[128 * LDK];
    __shared__ unsigned short Bs[TN * LDK];
    int t = threadIdx.x;
    int lane = t & 63, wave = t >> 6;
    int wm = (wave >> 1) * 64, wn = (wave & 1) * (TN / 2);
    int q = lane >> 4, l16 = lane & 15;
    int row0 = blockIdx.y * 128, col0 = blockIdx.x * TN;
    floatx4 acc[4][JN] = {};
    int sg = (t & 7) * 4;
    int sr = t >> 3;
    for (int kt = 0; kt < K; kt += 32) {
        #pragma unroll
        for (int p = 0; p < 4; p++) {
            int r = sr + p * 32;
            int ga = min(row0 + r, M - 1);
            *(ushortx4*)&As[r * LDK + sg] = *(const ushortx4*)(A + (size_t)ga * K + kt + sg);
        }
        #pragma unroll
        for (int p = 0; p < TN / 32; p++) {
            int r = sr + p * 32;
            *(ushortx4*)&Bs[r * LDK + sg] = *(const ushortx4*)(Bt + (size_t)(col0 + r) * K + kt + sg);
        }
        __syncthreads();
        bf16x8 af[4], bfr[JN];
        #pragma unroll
        for (int i = 0; i < 4; i++)
            af[i] = *(const bf16x8*)&As[(wm + i * 16 + l16) * LDK + q * 8];
        #pragma unroll
        for (int j = 0; j < JN; j++)
            bfr[j] = *(const bf16x8*)&Bs[(wn + j * 16 + l16) * LDK + q * 8];
        #pragma unroll
        for (int i = 0; i < 4; i++)
            #pragma unroll
            for (int j = 0; j < JN; j++)
                acc[i][j] = __builtin_amdgcn_mfma_f32_16x16x32_bf16(af[i], bfr[j], acc[i][j], 0, 0, 0);
        __syncthreads();
    }
    #pragma unroll
    for (int i = 0; i < 4; i++) {
        #pragma unroll
        for (int r = 0; r < 4; r++) {
            int grow = row0 + wm + i * 16 + q * 4 + r;
            if (grow < M) {
                unsigned short* cp = Cout + (size_t)grow * N + col0 + wn + l16;
                #pragma unroll
                for (int j = 0; j < JN; j++) cp[j * 16] = f2bf(acc[i][j][r]);
            }
        }
    }
}

// ---------------- layer-2 aggregation: 2-edge unrolled gather; fp32 out ----------------
__global__ __launch_bounds__(256) void agg2_kernel(const unsigned short* __restrict__ h2b,
        const float* __restrict__ wx, const float* __restrict__ den,
        const int* __restrict__ row_ptr, const int* __restrict__ col,
        const float* __restrict__ bias, float* __restrict__ out, int N) {
    int wid = (blockIdx.x * blockDim.x + threadIdx.x) >> 6;
    int lane = threadIdx.x & 63;
    if (wid >= N) return;
    int base = row_ptr[wid];
    int deg = row_ptr[wid + 1] - base;
    float4 a = {0, 0, 0, 0};
    int c = lane * 4;
    int i = 0;
    for (; i + 1 < deg; i += 2) {
        int s0 = col[base + i], s1 = col[base + i + 1];
        float x0 = wx[base + i], x1 = wx[base + i + 1];
        ushortx4 v0 = *(const ushortx4*)(h2b + (size_t)s0 * 256 + c);
        ushortx4 v1 = *(const ushortx4*)(h2b + (size_t)s1 * 256 + c);
        a.x += x0 * bf2f(v0[0]) + x1 * bf2f(v1[0]);
        a.y += x0 * bf2f(v0[1]) + x1 * bf2f(v1[1]);
        a.z += x0 * bf2f(v0[2]) + x1 * bf2f(v1[2]);
        a.w += x0 * bf2f(v0[3]) + x1 * bf2f(v1[3]);
    }
    if (i < deg) {
        int s0 = col[base + i];
        float x0 = wx[base + i];
        ushortx4 v0 = *(const ushortx4*)(h2b + (size_t)s0 * 256 + c);
        a.x += x0 * bf2f(v0[0]); a.y += x0 * bf2f(v0[1]);
        a.z += x0 * bf2f(v0[2]); a.w += x0 * bf2f(v0[3]);
    }
    float inv = 1.f / (den[wid] + 1e-16f);
    float4 o;
    o.x = eluf(a.x * inv + bias[c + 0]);
    o.y = eluf(a.y * inv + bias[c + 1]);
    o.z = eluf(a.z * inv + bias[c + 2]);
    o.w = eluf(a.w * inv + bias[c + 3]);
    *(float4*)(out + (size_t)wid * 256 + c) = o;
}

// ---------------- merged tail: influence head (8 nodes/block, 2 groups) | mean ----------------
__global__ __launch_bounds__(256) void tail_kernel(const float* __restrict__ h,
        const float* __restrict__ Wp1, const float* __restrict__ bp1,
        const float* __restrict__ Wp2, const float* __restrict__ bp2,
        float* __restrict__ gf, float* __restrict__ infl, int N) {
    int b = blockIdx.x;
    int nInfl = (N + 7) / 8;
    if (b < nInfl) {
        __shared__ float sh[8][256];
        __shared__ float red[8][128];
        int t = threadIdx.x;
        int g = t >> 7, tt = t & 127;
        int nb = b * 8 + g * 4;
        #pragma unroll
        for (int r = 0; r < 4; r++) {
            int n = nb + r;
            if (n < N) {
                sh[g * 4 + r][tt] = h[(size_t)n * 256 + tt];
                sh[g * 4 + r][tt + 128] = h[(size_t)n * 256 + tt + 128];
            }
        }
        __syncthreads();
        float acc0 = bp1[tt], acc1 = acc0, acc2 = acc0, acc3 = acc0;
        for (int k = 0; k < 256; k++) {
            float w = Wp1[k * 128 + tt];
            acc0 += sh[g * 4 + 0][k] * w;
            acc1 += sh[g * 4 + 1][k] * w;
            acc2 += sh[g * 4 + 2][k] * w;
            acc3 += sh[g * 4 + 3][k] * w;
        }
        float w2 = Wp2[tt];
        red[g * 4 + 0][tt] = fmaxf(acc0, 0.f) * w2;
        red[g * 4 + 1][tt] = fmaxf(acc1, 0.f) * w2;
        red[g * 4 + 2][tt] = fmaxf(acc2, 0.f) * w2;
        red[g * 4 + 3][tt] = fmaxf(acc3, 0.f) * w2;
        __syncthreads();
        for (int s = 64; s > 0; s >>= 1) {
            if (tt < s) {
                red[g * 4 + 0][tt] += red[g * 4 + 0][tt + s];
                red[g * 4 + 1][tt] += red[g * 4 + 1][tt + s];
                red[g * 4 + 2][tt] += red[g * 4 + 2][tt + s];
                red[g * 4 + 3][tt] += red[g * 4 + 3][tt + s];
            }
            __syncthreads();
        }
        if (tt < 4) {
            int n = nb + tt;
            if (n < N) {
                float v = red[g * 4 + tt][0] + bp2[0];
                infl[n] = 1.f / (1.f + __expf(-v));
            }
        }
    } else {
        int bb = b - nInfl;            // 0..79
        int c = threadIdx.x;
        int per = (N + 79) / 80;
        int n0 = bb * per;
        int n1 = min(N, n0 + per);
        float acc = 0.f;
        for (int n = n0; n < n1; n++) acc += h[(size_t)n * 256 + c];
        atomicAdd(&gf[c], acc * (1.0f / N));
    }
}

extern "C" void kernel_launch(void* const* d_in, const int* in_sizes, int n_in,
                              void* d_out, int out_size, void* d_ws, size_t ws_size,
                              hipStream_t stream) {
    const float* x   = (const float*)d_in[0];
    const int*   ei  = (const int*)d_in[1];
    const float* W1  = (const float*)d_in[2];
    const float* as1 = (const float*)d_in[3];
    const float* ad1 = (const float*)d_in[4];
    const float* b1  = (const float*)d_in[5];
    const float* W2  = (const float*)d_in[6];
    const float* as2 = (const float*)d_in[7];
    const float* ad2 = (const float*)d_in[8];
    const float* b2  = (const float*)d_in[9];
    const float* Wp1 = (const float*)d_in[10];
    const float* bp1 = (const float*)d_in[11];
    const float* Wp2 = (const float*)d_in[12];
    const float* bp2 = (const float*)d_in[13];

    const int N  = in_sizes[0] / 384;   // 20000
    const int E  = in_sizes[1] / 2;     // 320000
    const int Et = E + N;

    // ---- workspace layout ----
    char* wsp = (char*)d_ws;
    unsigned short* xb    = (unsigned short*)wsp; wsp += (size_t)N * 384  * sizeof(short);
    unsigned short* aggxn = (unsigned short*)wsp; wsp += (size_t)N * 1536 * sizeof(short);
    unsigned short* h1eb  = (unsigned short*)wsp; wsp += (size_t)N * 1024 * sizeof(short);
    unsigned short* h2b   = (unsigned short*)wsp; wsp += (size_t)N * 256  * sizeof(short);
    unsigned short* w1t   = (unsigned short*)wsp; wsp += (size_t)1024 * 384 * sizeof(short);
    unsigned short* w2t   = (unsigned short*)wsp; wsp += (size_t)256 * 1024 * sizeof(short);
    float* U   = (float*)wsp; wsp += (size_t)8 * 384 * sizeof(float);
    float* ss1 = (float*)wsp; wsp += (size_t)N * 4 * sizeof(float);
    float* sd1 = (float*)wsp; wsp += (size_t)N * 4 * sizeof(float);
    float* ss2 = (float*)wsp; wsp += (size_t)N * sizeof(float);
    float* sd2 = (float*)wsp; wsp += (size_t)N * sizeof(float);
    float* den1 = (float*)wsp; wsp += (size_t)N * 4 * sizeof(float);
    float* den2 = (float*)wsp; wsp += (size_t)N * sizeof(float);
    float* wx1  = (float*)wsp; wsp += (size_t)Et * 4 * sizeof(float);
    float* wx2  = (float*)wsp; wsp += (size_t)Et * sizeof(float);
    int* row_ptr = (int*)wsp; wsp += (size_t)(N + 1) * sizeof(int);
    int* cursor  = (int*)wsp; wsp += (size_t)N * sizeof(int);
    int* col     = (int*)wsp;

    float* out_h  = (float*)d_out;             // [N,256]
    float* out_gf = out_h + (size_t)N * 256;   // [256]
    float* out_if = out_gf + 256;              // [N]

    // prep (count + convert + transposes + U) ; cursor must be zeroed first
    hipMemsetAsync(cursor, 0, (size_t)N * sizeof(int), stream);
    int nA = (Et + 255) / 256;
    int nB = (N * 96 + 255) / 256;
    int nPrep = nA + nB + 384 + 256 + 96;
    prep_kernel<<<nPrep, 256, 0, stream>>>(ei, E, N, cursor, x, xb, W1, w1t, W2, w2t, as1, ad1, U);
    scan_kernel<<<1, 1024, 0, stream>>>(cursor, row_ptr, N);
    fill_kernel<<<nA, 256, 0, stream>>>(ei, E, N, cursor, col);

    // layer 1 (h1 never materialized)
    sU_kernel<<<(N + 3) / 4, 256, 0, stream>>>(xb, U, ss1, sd1, N);
    alpha1_kernel<<<(N + 3) / 4, 256, 0, stream>>>(ss1, sd1, row_ptr, col, wx1, den1, N);
    aggx_kernel<<<(N + 3) / 4, 256, 0, stream>>>(xb, wx1, den1, row_ptr, col, aggxn, N);
    gemm_l1<<<dim3(8, (N + 127) / 128), 256, 0, stream>>>(aggxn, w1t, b1, h1eb, N);

    // layer 2
    gemm_1t<64><<<dim3(4, (N + 127) / 128), 256, 0, stream>>>(h1eb, w2t, h2b, N, 256, 1024);
    s2_kernel<<<(N + 3) / 4, 256, 0, stream>>>(h2b, as2, ad2, ss2, sd2, N);
    alpha2_kernel<<<(N + 3) / 4, 256, 0, stream>>>(ss2, sd2, row_ptr, col, wx2, den2, N);
    agg2_kernel<<<(N + 3) / 4, 256, 0, stream>>>(h2b, wx2, den2, row_ptr, col, b2, out_h, N);

    // outputs 2 & 3 (merged)
    hipMemsetAsync(out_gf, 0, 256 * sizeof(float), stream);
    tail_kernel<<<(N + 7) / 8 + 80, 256, 0, stream>>>(out_h, Wp1, bp1, Wp2, bp2, out_gf, out_if, N);
}

// Round 9
// 442.530 us; speedup vs baseline: 1.2071x; 1.1985x over previous
//
#include <hip/hip_runtime.h>

#define NEG_SLOPE 0.2f

typedef __bf16 bf16x8 __attribute__((ext_vector_type(8)));
typedef float floatx4 __attribute__((ext_vector_type(4)));
typedef unsigned short ushortx4 __attribute__((ext_vector_type(4)));
typedef unsigned short ushortx8 __attribute__((ext_vector_type(8)));

__device__ __forceinline__ float eluf(float x) { return x > 0.f ? x : __expf(x) - 1.f; }
__device__ __forceinline__ float lrelu(float x) { return x > 0.f ? x : NEG_SLOPE * x; }

__device__ __forceinline__ unsigned short f2bf(float f) {
    unsigned u = __float_as_uint(f);
    u += 0x7FFFu + ((u >> 16) & 1u);           // round-to-nearest-even
    return (unsigned short)(u >> 16);
}
__device__ __forceinline__ float bf2f(unsigned short h) {
    return __uint_as_float(((unsigned)h) << 16);
}

// ================= merged prep: count | x->bf16 | W1^T | W2^T | U = W1·a =================
__global__ __launch_bounds__(256) void prep_kernel(
        const int* __restrict__ ei, int E, int N, int* __restrict__ counts,
        const float* __restrict__ x, unsigned short* __restrict__ xb,
        const float* __restrict__ W1, unsigned short* __restrict__ w1t,
        const float* __restrict__ W2, unsigned short* __restrict__ w2t,
        const float* __restrict__ as1, const float* __restrict__ ad1, float* __restrict__ U) {
    __shared__ float tile[32][33];
    int b = blockIdx.x;
    int t = threadIdx.x;
    int Et = E + N;
    int nA = (Et + 255) >> 8;
    int nB = (N * 96 + 255) >> 8;           // N*384/4 float4 groups
    if (b < nA) {
        int i = b * 256 + t;
        if (i < Et) {
            int d = (i < E) ? ei[E + i] : (i - E);
            atomicAdd(&counts[d], 1);
        }
    } else if (b < nA + nB) {
        int i = (b - nA) * 256 + t;
        if (i < N * 96) {
            float4 v = ((const float4*)x)[i];
            ushortx4 o;
            o[0] = f2bf(v.x); o[1] = f2bf(v.y); o[2] = f2bf(v.z); o[3] = f2bf(v.w);
            *(ushortx4*)(xb + (size_t)i * 4) = o;
        }
    } else if (b < nA + nB + 384) {
        int idx = b - nA - nB;
        int n0 = (idx & 31) * 32, k0 = (idx >> 5) * 32;
        int tx = t & 31, ty = t >> 5;
        #pragma unroll
        for (int i = 0; i < 32; i += 8)
            tile[ty + i][tx] = W1[(size_t)(k0 + ty + i) * 1024 + n0 + tx];
        __syncthreads();
        #pragma unroll
        for (int i = 0; i < 32; i += 8)
            w1t[(size_t)(n0 + ty + i) * 384 + k0 + tx] = f2bf(tile[tx][ty + i]);
    } else if (b < nA + nB + 384 + 256) {
        int idx = b - nA - nB - 384;
        int n0 = (idx & 7) * 32, k0 = (idx >> 3) * 32;
        int tx = t & 31, ty = t >> 5;
        #pragma unroll
        for (int i = 0; i < 32; i += 8)
            tile[ty + i][tx] = W2[(size_t)(k0 + ty + i) * 256 + n0 + tx];
        __syncthreads();
        #pragma unroll
        for (int i = 0; i < 32; i += 8)
            w2t[(size_t)(n0 + ty + i) * 1024 + k0 + tx] = f2bf(tile[tx][ty + i]);
    } else {
        // U[8][384]: U[r][k] = sum_c W1[k][h*256+c] * a[h][c], h=r&3, a = src(r<4)/dst
        int idx = b - nA - nB - 384 - 256;
        int k = idx * 4 + (t >> 6);
        int lane = t & 63;
        #pragma unroll
        for (int r = 0; r < 8; r++) {
            int h = r & 3;
            const float* a = (r < 4 ? as1 : ad1) + h * 256 + lane * 4;
            const float* w = W1 + (size_t)k * 1024 + h * 256 + lane * 4;
            float4 wv = *(const float4*)w;
            float4 av = *(const float4*)a;
            float p = wv.x * av.x + wv.y * av.y + wv.z * av.z + wv.w * av.w;
            #pragma unroll
            for (int off = 32; off; off >>= 1) p += __shfl_xor(p, off);
            if (lane == 0) U[r * 384 + k] = p;
        }
    }
}

// single 1024-thread block; wave-shuffle scan
__global__ void scan_kernel(int* __restrict__ counts_cursor, int* __restrict__ row_ptr, int N) {
    __shared__ int s_wsum[16];
    __shared__ int s_carry;
    int t = threadIdx.x;
    int lane = t & 63, wid = t >> 6;
    if (t == 0) { s_carry = 0; row_ptr[0] = 0; }
    __syncthreads();
    for (int start = 0; start < N; start += 1024) {
        int i = start + t;
        int v = (i < N) ? counts_cursor[i] : 0;
        int s = v;
        #pragma unroll
        for (int d = 1; d < 64; d <<= 1) {
            int u = __shfl_up(s, d);
            if (lane >= d) s += u;
        }
        if (lane == 63) s_wsum[wid] = s;
        __syncthreads();
        if (wid == 0) {
            int w = (lane < 16) ? s_wsum[lane] : 0;
            #pragma unroll
            for (int d = 1; d < 16; d <<= 1) {
                int u = __shfl_up(w, d);
                if (lane >= d) w += u;
            }
            if (lane < 16) s_wsum[lane] = w;
        }
        __syncthreads();
        int incl = s + (wid ? s_wsum[wid - 1] : 0) + s_carry;
        if (i < N) { row_ptr[i + 1] = incl; counts_cursor[i] = incl - v; }
        __syncthreads();
        if (t == 0) s_carry += s_wsum[15];
        __syncthreads();
    }
}

__global__ void fill_kernel(const int* __restrict__ ei, int E, int N,
                            int* __restrict__ cursor, int* __restrict__ col) {
    int i = blockIdx.x * blockDim.x + threadIdx.x;
    int Et = E + N;
    if (i >= Et) return;
    int s, d;
    if (i < E) { s = ei[i]; d = ei[E + i]; } else { s = d = i - E; }
    int pos = atomicAdd(&cursor[d], 1);
    col[pos] = s;
}

// ---------------- logits via U: ss1[n][h]=x[n]·U[h], sd1[n][h]=x[n]·U[4+h] ----------------
__global__ void sU_kernel(const unsigned short* __restrict__ xb, const float* __restrict__ U,
                          float* __restrict__ ss1, float* __restrict__ sd1, int N) {
    int wid = (blockIdx.x * blockDim.x + threadIdx.x) >> 6;
    int lane = threadIdx.x & 63;
    if (wid >= N) return;
    int half = lane >> 5, l32 = lane & 31;
    int c0 = l32 * 12;
    const unsigned short* row = xb + (size_t)wid * 384 + c0;
    ushortx8 v8 = *(const ushortx8*)row;
    ushortx4 v4 = *(const ushortx4*)(row + 8);
    float xv[12];
    #pragma unroll
    for (int j = 0; j < 8; j++) xv[j] = bf2f(v8[j]);
    #pragma unroll
    for (int j = 0; j < 4; j++) xv[8 + j] = bf2f(v4[j]);
    float p[4];
    #pragma unroll
    for (int r = 0; r < 4; r++) {
        const float* u = U + (half * 4 + r) * 384 + c0;
        float s = 0.f;
        #pragma unroll
        for (int j = 0; j < 12; j++) s += xv[j] * u[j];
        #pragma unroll
        for (int off = 16; off; off >>= 1) s += __shfl_xor(s, off);
        p[r] = s;
    }
    if (l32 == 0) {
        float* dst = half ? (sd1 + wid * 4) : (ss1 + wid * 4);
        dst[0] = p[0]; dst[1] = p[1]; dst[2] = p[2]; dst[3] = p[3];
    }
}

// ---------------- per-node attention logits, layer 2 (H=1, C=256), bf16 h2 ----------------
__global__ void s2_kernel(const unsigned short* __restrict__ h2b, const float* __restrict__ a_src,
                          const float* __restrict__ a_dst, float* __restrict__ ssrc,
                          float* __restrict__ sdst, int N) {
    int wid = (blockIdx.x * blockDim.x + threadIdx.x) >> 6;
    int lane = threadIdx.x & 63;
    if (wid >= N) return;
    ushortx4 v = *(const ushortx4*)(h2b + (size_t)wid * 256 + lane * 4);
    float4 a = ((const float4*)a_src)[lane];
    float4 d = ((const float4*)a_dst)[lane];
    float v0 = bf2f(v[0]), v1 = bf2f(v[1]), v2 = bf2f(v[2]), v3 = bf2f(v[3]);
    float s = v0 * a.x + v1 * a.y + v2 * a.z + v3 * a.w;
    float t = v0 * d.x + v1 * d.y + v2 * d.z + v3 * d.w;
    for (int off = 32; off; off >>= 1) { s += __shfl_xor(s, off); t += __shfl_xor(t, off); }
    if (lane == 0) { ssrc[wid] = s; sdst[wid] = t; }
}

// ---------------- per-edge softmax weights, layer 1 (H=4) ----------------
__global__ __launch_bounds__(256) void alpha1_kernel(const float* __restrict__ ssrc,
        const float* __restrict__ sdst, const int* __restrict__ row_ptr,
        const int* __restrict__ col, float* __restrict__ wx, float* __restrict__ den, int N) {
    int wid = (blockIdx.x * blockDim.x + threadIdx.x) >> 6;
    int lane = threadIdx.x & 63;
    if (wid >= N) return;
    int base = row_ptr[wid];
    int deg = row_ptr[wid + 1] - base;
    float sd0 = sdst[wid * 4 + 0], sd1 = sdst[wid * 4 + 1];
    float sd2 = sdst[wid * 4 + 2], sd3 = sdst[wid * 4 + 3];
    float m0 = -1e30f, m1 = -1e30f, m2 = -1e30f, m3 = -1e30f;
    for (int i = lane; i < deg; i += 64) {
        int s = col[base + i];
        const float* sp = ssrc + s * 4;
        m0 = fmaxf(m0, lrelu(sp[0] + sd0));
        m1 = fmaxf(m1, lrelu(sp[1] + sd1));
        m2 = fmaxf(m2, lrelu(sp[2] + sd2));
        m3 = fmaxf(m3, lrelu(sp[3] + sd3));
    }
    #pragma unroll
    for (int off = 32; off; off >>= 1) {
        m0 = fmaxf(m0, __shfl_xor(m0, off));
        m1 = fmaxf(m1, __shfl_xor(m1, off));
        m2 = fmaxf(m2, __shfl_xor(m2, off));
        m3 = fmaxf(m3, __shfl_xor(m3, off));
    }
    float d0 = 0.f, d1 = 0.f, d2 = 0.f, d3 = 0.f;
    for (int i = lane; i < deg; i += 64) {
        int s = col[base + i];
        const float* sp = ssrc + s * 4;
        float4 w4;
        w4.x = __expf(lrelu(sp[0] + sd0) - m0); d0 += w4.x;
        w4.y = __expf(lrelu(sp[1] + sd1) - m1); d1 += w4.y;
        w4.z = __expf(lrelu(sp[2] + sd2) - m2); d2 += w4.z;
        w4.w = __expf(lrelu(sp[3] + sd3) - m3); d3 += w4.w;
        *(float4*)(wx + (size_t)(base + i) * 4) = w4;
    }
    #pragma unroll
    for (int off = 32; off; off >>= 1) {
        d0 += __shfl_xor(d0, off);
        d1 += __shfl_xor(d1, off);
        d2 += __shfl_xor(d2, off);
        d3 += __shfl_xor(d3, off);
    }
    if (lane == 0) {
        den[wid * 4 + 0] = d0; den[wid * 4 + 1] = d1;
        den[wid * 4 + 2] = d2; den[wid * 4 + 3] = d3;
    }
}

// ---------------- per-edge softmax weights, layer 2 (H=1) ----------------
__global__ __launch_bounds__(256) void alpha2_kernel(const float* __restrict__ ssrc,
        const float* __restrict__ sdst, const int* __restrict__ row_ptr,
        const int* __restrict__ col, float* __restrict__ wx, float* __restrict__ den, int N) {
    int wid = (blockIdx.x * blockDim.x + threadIdx.x) >> 6;
    int lane = threadIdx.x & 63;
    if (wid >= N) return;
    int base = row_ptr[wid];
    int deg = row_ptr[wid + 1] - base;
    float sd = sdst[wid];
    float m = -1e30f;
    for (int i = lane; i < deg; i += 64) {
        int s = col[base + i];
        m = fmaxf(m, lrelu(ssrc[s] + sd));
    }
    #pragma unroll
    for (int off = 32; off; off >>= 1) m = fmaxf(m, __shfl_xor(m, off));
    float d = 0.f;
    for (int i = lane; i < deg; i += 64) {
        int s = col[base + i];
        float x = __expf(lrelu(ssrc[s] + sd) - m);
        d += x;
        wx[base + i] = x;
    }
    #pragma unroll
    for (int off = 32; off; off >>= 1) d += __shfl_xor(d, off);
    if (lane == 0) den[wid] = d;
}

// ---------------- aggx: per-head weighted aggregation of x rows (384 ch) ----------------
// NOTE: epilogue must NOT index acc[] with a runtime value (half) — that demotes the
// whole accumulator to scratch (r7/r8: VGPR=40, 595 MB phantom WRITE_SIZE). All acc
// indices below are compile-time; runtime head selection is done with cndmask selects.
__global__ __launch_bounds__(256) void aggx_kernel(const unsigned short* __restrict__ xb,
        const float* __restrict__ wx, const float* __restrict__ den,
        const int* __restrict__ row_ptr, const int* __restrict__ col,
        unsigned short* __restrict__ aggxn, int N) {
    __shared__ unsigned short lds[4][1536];
    int t = threadIdx.x;
    int wv = t >> 6;
    int wid = blockIdx.x * 4 + wv;
    int lane = t & 63;
    bool active = wid < N;
    int half = lane >> 5, l32 = lane & 31;
    int c0 = l32 * 12;
    if (active) {
        int base = row_ptr[wid];
        int deg = row_ptr[wid + 1] - base;
        float acc[4][12] = {};
        for (int i = half; i < deg; i += 2) {
            int e = base + i;
            int s = col[e];
            float4 w4 = *(const float4*)(wx + (size_t)e * 4);
            const unsigned short* row = xb + (size_t)s * 384 + c0;
            ushortx8 v8 = *(const ushortx8*)row;
            ushortx4 v4 = *(const ushortx4*)(row + 8);
            float xv[12];
            #pragma unroll
            for (int j = 0; j < 8; j++) xv[j] = bf2f(v8[j]);
            #pragma unroll
            for (int j = 0; j < 4; j++) xv[8 + j] = bf2f(v4[j]);
            #pragma unroll
            for (int j = 0; j < 12; j++) {
                acc[0][j] += w4.x * xv[j];
                acc[1][j] += w4.y * xv[j];
                acc[2][j] += w4.z * xv[j];
                acc[3][j] += w4.w * xv[j];
            }
        }
        // combine the two halves (same channels at lane ^ 32)
        #pragma unroll
        for (int h = 0; h < 4; h++)
            #pragma unroll
            for (int j = 0; j < 12; j++)
                acc[h][j] += __shfl_xor(acc[h][j], 32);
        // each half stages 2 normalized heads into LDS; acc read with constant indices
        #pragma unroll
        for (int hh = 0; hh < 2; hh++) {
            int h = half * 2 + hh;   // runtime — used for LDS addressing / den only
            float inv = 1.f / (den[wid * 4 + h] + 1e-16f);
            ushortx8 o8; ushortx4 o4;
            #pragma unroll
            for (int j = 0; j < 8; j++) {
                float v = half ? acc[2 + hh][j] : acc[hh][j];
                o8[j] = f2bf(v * inv);
            }
            #pragma unroll
            for (int j = 0; j < 4; j++) {
                float v = half ? acc[2 + hh][8 + j] : acc[hh][8 + j];
                o4[j] = f2bf(v * inv);
            }
            unsigned short* lp = &lds[wv][h * 384 + c0];
            *(ushortx8*)lp = o8;
            *(ushortx4*)(lp + 8) = o4;
        }
    }
    __syncthreads();
    // block-coalesced store: 3 x (256 threads x 16B) covering 4 consecutive node-rows
    size_t blockBase = (size_t)blockIdx.x * 4 * 1536;
    const unsigned short* lflat = &lds[0][0];
    #pragma unroll
    for (int j = 0; j < 3; j++) {
        int so = j * 2048 + t * 8;            // short offset in [0, 6144)
        int node = blockIdx.x * 4 + so / 1536;
        if (node < N)
            *(ushortx8*)(aggxn + blockBase + so) = *(const ushortx8*)(lflat + so);
    }
}

#define LDK 40  // 32 + 8 pad (shorts) -> 80 B row stride, 2-way (free) frag-read conflicts

// ---------------- layer-1 head-GEMM: h1e = elu(aggxn_head @ w1t_cols + b1), bf16 out ----------------
__global__ __launch_bounds__(256) void gemm_l1(const unsigned short* __restrict__ A,
        const unsigned short* __restrict__ Bt, const float* __restrict__ bias,
        unsigned short* __restrict__ Cout, int M) {
    __shared__ unsigned short As[128 * LDK];
    __shared__ unsigned short Bs[128 * LDK];
    int t = threadIdx.x;
    int lane = t & 63, wave = t >> 6;
    int wm = (wave >> 1) * 64, wn = (wave & 1) * 64;
    int q = lane >> 4, l16 = lane & 15;
    int row0 = blockIdx.y * 128, col0 = blockIdx.x * 128;
    int hoff = (col0 >> 8) * 384;
    floatx4 acc[4][4] = {};
    int sg = (t & 7) * 4;
    int sr = t >> 3;
    for (int kt = 0; kt < 384; kt += 32) {
        #pragma unroll
        for (int p = 0; p < 4; p++) {
            int r = sr + p * 32;
            int ga = min(row0 + r, M - 1);
            *(ushortx4*)&As[r * LDK + sg] = *(const ushortx4*)(A + (size_t)ga * 1536 + hoff + kt + sg);
        }
        #pragma unroll
        for (int p = 0; p < 4; p++) {
            int r = sr + p * 32;
            *(ushortx4*)&Bs[r * LDK + sg] = *(const ushortx4*)(Bt + (size_t)(col0 + r) * 384 + kt + sg);
        }
        __syncthreads();
        bf16x8 af[4], bfr[4];
        #pragma unroll
        for (int i = 0; i < 4; i++)
            af[i] = *(const bf16x8*)&As[(wm + i * 16 + l16) * LDK + q * 8];
        #pragma unroll
        for (int j = 0; j < 4; j++)
            bfr[j] = *(const bf16x8*)&Bs[(wn + j * 16 + l16) * LDK + q * 8];
        #pragma unroll
        for (int i = 0; i < 4; i++)
            #pragma unroll
            for (int j = 0; j < 4; j++)
                acc[i][j] = __builtin_amdgcn_mfma_f32_16x16x32_bf16(af[i], bfr[j], acc[i][j], 0, 0, 0);
        __syncthreads();
    }
    float bj[4];
    #pragma unroll
    for (int j = 0; j < 4; j++) bj[j] = bias[col0 + wn + l16 + j * 16];
    #pragma unroll
    for (int i = 0; i < 4; i++) {
        #pragma unroll
        for (int r = 0; r < 4; r++) {
            int grow = row0 + wm + i * 16 + q * 4 + r;
            if (grow < M) {
                unsigned short* cp = Cout + (size_t)grow * 1024 + col0 + wn + l16;
                #pragma unroll
                for (int j = 0; j < 4; j++) cp[j * 16] = f2bf(eluf(acc[i][j][r] + bj[j]));
            }
        }
    }
}

// ---------------- bf16 MFMA GEMM (layer 2): C = A @ Bt^T, bf16 out ----------------
template <int TN>
__global__ __launch_bounds__(256) void gemm_1t(const unsigned short* __restrict__ A,
        const unsigned short* __restrict__ Bt, unsigned short* __restrict__ Cout,
        int M, int N, int K) {
    constexpr int JN = TN / 32;
    __shared__ unsigned short As[128 * LDK];
    __shared__ unsigned short Bs[TN * LDK];
    int t = threadIdx.x;
    int lane = t & 63, wave = t >> 6;
    int wm = (wave >> 1) * 64, wn = (wave & 1) * (TN / 2);
    int q = lane >> 4, l16 = lane & 15;
    int row0 = blockIdx.y * 128, col0 = blockIdx.x * TN;
    floatx4 acc[4][JN] = {};
    int sg = (t & 7) * 4;
    int sr = t >> 3;
    for (int kt = 0; kt < K; kt += 32) {
        #pragma unroll
        for (int p = 0; p < 4; p++) {
            int r = sr + p * 32;
            int ga = min(row0 + r, M - 1);
            *(ushortx4*)&As[r * LDK + sg] = *(const ushortx4*)(A + (size_t)ga * K + kt + sg);
        }
        #pragma unroll
        for (int p = 0; p < TN / 32; p++) {
            int r = sr + p * 32;
            *(ushortx4*)&Bs[r * LDK + sg] = *(const ushortx4*)(Bt + (size_t)(col0 + r) * K + kt + sg);
        }
        __syncthreads();
        bf16x8 af[4], bfr[JN];
        #pragma unroll
        for (int i = 0; i < 4; i++)
            af[i] = *(const bf16x8*)&As[(wm + i * 16 + l16) * LDK + q * 8];
        #pragma unroll
        for (int j = 0; j < JN; j++)
            bfr[j] = *(const bf16x8*)&Bs[(wn + j * 16 + l16) * LDK + q * 8];
        #pragma unroll
        for (int i = 0; i < 4; i++)
            #pragma unroll
            for (int j = 0; j < JN; j++)
                acc[i][j] = __builtin_amdgcn_mfma_f32_16x16x32_bf16(af[i], bfr[j], acc[i][j], 0, 0, 0);
        __syncthreads();
    }
    #pragma unroll
    for (int i = 0; i < 4; i++) {
        #pragma unroll
        for (int r = 0; r < 4; r++) {
            int grow = row0 + wm + i * 16 + q * 4 + r;
            if (grow < M) {
                unsigned short* cp = Cout + (size_t)grow * N + col0 + wn + l16;
                #pragma unroll
                for (int j = 0; j < JN; j++) cp[j * 16] = f2bf(acc[i][j][r]);
            }
        }
    }
}

// ---------------- layer-2 aggregation: 2-edge unrolled gather; fp32 out ----------------
__global__ __launch_bounds__(256) void agg2_kernel(const unsigned short* __restrict__ h2b,
        const float* __restrict__ wx, const float* __restrict__ den,
        const int* __restrict__ row_ptr, const int* __restrict__ col,
        const float* __restrict__ bias, float* __restrict__ out, int N) {
    int wid = (blockIdx.x * blockDim.x + threadIdx.x) >> 6;
    int lane = threadIdx.x & 63;
    if (wid >= N) return;
    int base = row_ptr[wid];
    int deg = row_ptr[wid + 1] - base;
    float4 a = {0, 0, 0, 0};
    int c = lane * 4;
    int i = 0;
    for (; i + 1 < deg; i += 2) {
        int s0 = col[base + i], s1 = col[base + i + 1];
        float x0 = wx[base + i], x1 = wx[base + i + 1];
        ushortx4 v0 = *(const ushortx4*)(h2b + (size_t)s0 * 256 + c);
        ushortx4 v1 = *(const ushortx4*)(h2b + (size_t)s1 * 256 + c);
        a.x += x0 * bf2f(v0[0]) + x1 * bf2f(v1[0]);
        a.y += x0 * bf2f(v0[1]) + x1 * bf2f(v1[1]);
        a.z += x0 * bf2f(v0[2]) + x1 * bf2f(v1[2]);
        a.w += x0 * bf2f(v0[3]) + x1 * bf2f(v1[3]);
    }
    if (i < deg) {
        int s0 = col[base + i];
        float x0 = wx[base + i];
        ushortx4 v0 = *(const ushortx4*)(h2b + (size_t)s0 * 256 + c);
        a.x += x0 * bf2f(v0[0]); a.y += x0 * bf2f(v0[1]);
        a.z += x0 * bf2f(v0[2]); a.w += x0 * bf2f(v0[3]);
    }
    float inv = 1.f / (den[wid] + 1e-16f);
    float4 o;
    o.x = eluf(a.x * inv + bias[c + 0]);
    o.y = eluf(a.y * inv + bias[c + 1]);
    o.z = eluf(a.z * inv + bias[c + 2]);
    o.w = eluf(a.w * inv + bias[c + 3]);
    *(float4*)(out + (size_t)wid * 256 + c) = o;
}

// ---------------- merged tail: influence head (8 nodes/block, 2 groups) | mean ----------------
__global__ __launch_bounds__(256) void tail_kernel(const float* __restrict__ h,
        const float* __restrict__ Wp1, const float* __restrict__ bp1,
        const float* __restrict__ Wp2, const float* __restrict__ bp2,
        float* __restrict__ gf, float* __restrict__ infl, int N) {
    int b = blockIdx.x;
    int nInfl = (N + 7) / 8;
    if (b < nInfl) {
        __shared__ float sh[8][256];
        __shared__ float red[8][128];
        int t = threadIdx.x;
        int g = t >> 7, tt = t & 127;
        int nb = b * 8 + g * 4;
        #pragma unroll
        for (int r = 0; r < 4; r++) {
            int n = nb + r;
            if (n < N) {
                sh[g * 4 + r][tt] = h[(size_t)n * 256 + tt];
                sh[g * 4 + r][tt + 128] = h[(size_t)n * 256 + tt + 128];
            }
        }
        __syncthreads();
        float acc0 = bp1[tt], acc1 = acc0, acc2 = acc0, acc3 = acc0;
        for (int k = 0; k < 256; k++) {
            float w = Wp1[k * 128 + tt];
            acc0 += sh[g * 4 + 0][k] * w;
            acc1 += sh[g * 4 + 1][k] * w;
            acc2 += sh[g * 4 + 2][k] * w;
            acc3 += sh[g * 4 + 3][k] * w;
        }
        float w2 = Wp2[tt];
        red[g * 4 + 0][tt] = fmaxf(acc0, 0.f) * w2;
        red[g * 4 + 1][tt] = fmaxf(acc1, 0.f) * w2;
        red[g * 4 + 2][tt] = fmaxf(acc2, 0.f) * w2;
        red[g * 4 + 3][tt] = fmaxf(acc3, 0.f) * w2;
        __syncthreads();
        for (int s = 64; s > 0; s >>= 1) {
            if (tt < s) {
                red[g * 4 + 0][tt] += red[g * 4 + 0][tt + s];
                red[g * 4 + 1][tt] += red[g * 4 + 1][tt + s];
                red[g * 4 + 2][tt] += red[g * 4 + 2][tt + s];
                red[g * 4 + 3][tt] += red[g * 4 + 3][tt + s];
            }
            __syncthreads();
        }
        if (tt < 4) {
            int n = nb + tt;
            if (n < N) {
                float v = red[g * 4 + tt][0] + bp2[0];
                infl[n] = 1.f / (1.f + __expf(-v));
            }
        }
    } else {
        int bb = b - nInfl;            // 0..79
        int c = threadIdx.x;
        int per = (N + 79) / 80;
        int n0 = bb * per;
        int n1 = min(N, n0 + per);
        float acc = 0.f;
        for (int n = n0; n < n1; n++) acc += h[(size_t)n * 256 + c];
        atomicAdd(&gf[c], acc * (1.0f / N));
    }
}

extern "C" void kernel_launch(void* const* d_in, const int* in_sizes, int n_in,
                              void* d_out, int out_size, void* d_ws, size_t ws_size,
                              hipStream_t stream) {
    const float* x   = (const float*)d_in[0];
    const int*   ei  = (const int*)d_in[1];
    const float* W1  = (const float*)d_in[2];
    const float* as1 = (const float*)d_in[3];
    const float* ad1 = (const float*)d_in[4];
    const float* b1  = (const float*)d_in[5];
    const float* W2  = (const float*)d_in[6];
    const float* as2 = (const float*)d_in[7];
    const float* ad2 = (const float*)d_in[8];
    const float* b2  = (const float*)d_in[9];
    const float* Wp1 = (const float*)d_in[10];
    const float* bp1 = (const float*)d_in[11];
    const float* Wp2 = (const float*)d_in[12];
    const float* bp2 = (const float*)d_in[13];

    const int N  = in_sizes[0] / 384;   // 20000
    const int E  = in_sizes[1] / 2;     // 320000
    const int Et = E + N;

    // ---- workspace layout ----
    char* wsp = (char*)d_ws;
    unsigned short* xb    = (unsigned short*)wsp; wsp += (size_t)N * 384  * sizeof(short);
    unsigned short* aggxn = (unsigned short*)wsp; wsp += (size_t)N * 1536 * sizeof(short);
    unsigned short* h1eb  = (unsigned short*)wsp; wsp += (size_t)N * 1024 * sizeof(short);
    unsigned short* h2b   = (unsigned short*)wsp; wsp += (size_t)N * 256  * sizeof(short);
    unsigned short* w1t   = (unsigned short*)wsp; wsp += (size_t)1024 * 384 * sizeof(short);
    unsigned short* w2t   = (unsigned short*)wsp; wsp += (size_t)256 * 1024 * sizeof(short);
    float* U   = (float*)wsp; wsp += (size_t)8 * 384 * sizeof(float);
    float* ss1 = (float*)wsp; wsp += (size_t)N * 4 * sizeof(float);
    float* sd1 = (float*)wsp; wsp += (size_t)N * 4 * sizeof(float);
    float* ss2 = (float*)wsp; wsp += (size_t)N * sizeof(float);
    float* sd2 = (float*)wsp; wsp += (size_t)N * sizeof(float);
    float* den1 = (float*)wsp; wsp += (size_t)N * 4 * sizeof(float);
    float* den2 = (float*)wsp; wsp += (size_t)N * sizeof(float);
    float* wx1  = (float*)wsp; wsp += (size_t)Et * 4 * sizeof(float);
    float* wx2  = (float*)wsp; wsp += (size_t)Et * sizeof(float);
    int* row_ptr = (int*)wsp; wsp += (size_t)(N + 1) * sizeof(int);
    int* cursor  = (int*)wsp; wsp += (size_t)N * sizeof(int);
    int* col     = (int*)wsp;

    float* out_h  = (float*)d_out;             // [N,256]
    float* out_gf = out_h + (size_t)N * 256;   // [256]
    float* out_if = out_gf + 256;              // [N]

    // prep (count + convert + transposes + U) ; cursor must be zeroed first
    hipMemsetAsync(cursor, 0, (size_t)N * sizeof(int), stream);
    int nA = (Et + 255) / 256;
    int nB = (N * 96 + 255) / 256;
    int nPrep = nA + nB + 384 + 256 + 96;
    prep_kernel<<<nPrep, 256, 0, stream>>>(ei, E, N, cursor, x, xb, W1, w1t, W2, w2t, as1, ad1, U);
    scan_kernel<<<1, 1024, 0, stream>>>(cursor, row_ptr, N);
    fill_kernel<<<nA, 256, 0, stream>>>(ei, E, N, cursor, col);

    // layer 1 (h1 never materialized)
    sU_kernel<<<(N + 3) / 4, 256, 0, stream>>>(xb, U, ss1, sd1, N);
    alpha1_kernel<<<(N + 3) / 4, 256, 0, stream>>>(ss1, sd1, row_ptr, col, wx1, den1, N);
    aggx_kernel<<<(N + 3) / 4, 256, 0, stream>>>(xb, wx1, den1, row_ptr, col, aggxn, N);
    gemm_l1<<<dim3(8, (N + 127) / 128), 256, 0, stream>>>(aggxn, w1t, b1, h1eb, N);

    // layer 2
    gemm_1t<64><<<dim3(4, (N + 127) / 128), 256, 0, stream>>>(h1eb, w2t, h2b, N, 256, 1024);
    s2_kernel<<<(N + 3) / 4, 256, 0, stream>>>(h2b, as2, ad2, ss2, sd2, N);
    alpha2_kernel<<<(N + 3) / 4, 256, 0, stream>>>(ss2, sd2, row_ptr, col, wx2, den2, N);
    agg2_kernel<<<(N + 3) / 4, 256, 0, stream>>>(h2b, wx2, den2, row_ptr, col, b2, out_h, N);

    // outputs 2 & 3 (merged)
    hipMemsetAsync(out_gf, 0, 256 * sizeof(float), stream);
    tail_kernel<<<(N + 7) / 8 + 80, 256, 0, stream>>>(out_h, Wp1, bp1, Wp2, bp2, out_gf, out_if, N);
}

// Round 10
// 423.385 us; speedup vs baseline: 1.2617x; 1.0452x over previous
//
#include <hip/hip_runtime.h>

#define NEG_SLOPE 0.2f

typedef __bf16 bf16x8 __attribute__((ext_vector_type(8)));
typedef float floatx4 __attribute__((ext_vector_type(4)));
typedef unsigned short ushortx4 __attribute__((ext_vector_type(4)));
typedef unsigned short ushortx8 __attribute__((ext_vector_type(8)));

__device__ __forceinline__ float eluf(float x) { return x > 0.f ? x : __expf(x) - 1.f; }
__device__ __forceinline__ float lrelu(float x) { return x > 0.f ? x : NEG_SLOPE * x; }

__device__ __forceinline__ unsigned short f2bf(float f) {
    unsigned u = __float_as_uint(f);
    u += 0x7FFFu + ((u >> 16) & 1u);           // round-to-nearest-even
    return (unsigned short)(u >> 16);
}
__device__ __forceinline__ float bf2f(unsigned short h) {
    return __uint_as_float(((unsigned)h) << 16);
}

// ========= merged prep: count | x->bf16 | W1^T | W2^T | Wp1^T | U = W1·a =========
__global__ __launch_bounds__(256) void prep_kernel(
        const int* __restrict__ ei, int E, int N, int* __restrict__ counts,
        const float* __restrict__ x, unsigned short* __restrict__ xb,
        const float* __restrict__ W1, unsigned short* __restrict__ w1t,
        const float* __restrict__ W2, unsigned short* __restrict__ w2t,
        const float* __restrict__ Wp1, unsigned short* __restrict__ wp1t,
        const float* __restrict__ as1, const float* __restrict__ ad1, float* __restrict__ U) {
    __shared__ float tile[32][33];
    int b = blockIdx.x;
    int t = threadIdx.x;
    int Et = E + N;
    int nA = (Et + 255) >> 8;
    int nB = (N * 96 + 255) >> 8;           // N*384/4 float4 groups
    if (b < nA) {
        int i = b * 256 + t;
        if (i < Et) {
            int d = (i < E) ? ei[E + i] : (i - E);
            atomicAdd(&counts[d], 1);
        }
    } else if (b < nA + nB) {
        int i = (b - nA) * 256 + t;
        if (i < N * 96) {
            float4 v = ((const float4*)x)[i];
            ushortx4 o;
            o[0] = f2bf(v.x); o[1] = f2bf(v.y); o[2] = f2bf(v.z); o[3] = f2bf(v.w);
            *(ushortx4*)(xb + (size_t)i * 4) = o;
        }
    } else if (b < nA + nB + 384) {
        int idx = b - nA - nB;
        int n0 = (idx & 31) * 32, k0 = (idx >> 5) * 32;
        int tx = t & 31, ty = t >> 5;
        #pragma unroll
        for (int i = 0; i < 32; i += 8)
            tile[ty + i][tx] = W1[(size_t)(k0 + ty + i) * 1024 + n0 + tx];
        __syncthreads();
        #pragma unroll
        for (int i = 0; i < 32; i += 8)
            w1t[(size_t)(n0 + ty + i) * 384 + k0 + tx] = f2bf(tile[tx][ty + i]);
    } else if (b < nA + nB + 384 + 256) {
        int idx = b - nA - nB - 384;
        int n0 = (idx & 7) * 32, k0 = (idx >> 3) * 32;
        int tx = t & 31, ty = t >> 5;
        #pragma unroll
        for (int i = 0; i < 32; i += 8)
            tile[ty + i][tx] = W2[(size_t)(k0 + ty + i) * 256 + n0 + tx];
        __syncthreads();
        #pragma unroll
        for (int i = 0; i < 32; i += 8)
            w2t[(size_t)(n0 + ty + i) * 1024 + k0 + tx] = f2bf(tile[tx][ty + i]);
    } else if (b < nA + nB + 384 + 256 + 32) {
        // Wp1 [256][128] -> wp1t [128][256] bf16
        int idx = b - nA - nB - 384 - 256;
        int n0 = (idx & 3) * 32, k0 = (idx >> 2) * 32;
        int tx = t & 31, ty = t >> 5;
        #pragma unroll
        for (int i = 0; i < 32; i += 8)
            tile[ty + i][tx] = Wp1[(size_t)(k0 + ty + i) * 128 + n0 + tx];
        __syncthreads();
        #pragma unroll
        for (int i = 0; i < 32; i += 8)
            wp1t[(size_t)(n0 + ty + i) * 256 + k0 + tx] = f2bf(tile[tx][ty + i]);
    } else {
        // U[8][384]: U[r][k] = sum_c W1[k][h*256+c] * a[h][c], h=r&3, a = src(r<4)/dst
        int idx = b - nA - nB - 384 - 256 - 32;
        int k = idx * 4 + (t >> 6);
        int lane = t & 63;
        #pragma unroll
        for (int r = 0; r < 8; r++) {
            int h = r & 3;
            const float* a = (r < 4 ? as1 : ad1) + h * 256 + lane * 4;
            const float* w = W1 + (size_t)k * 1024 + h * 256 + lane * 4;
            float4 wv = *(const float4*)w;
            float4 av = *(const float4*)a;
            float p = wv.x * av.x + wv.y * av.y + wv.z * av.z + wv.w * av.w;
            #pragma unroll
            for (int off = 32; off; off >>= 1) p += __shfl_xor(p, off);
            if (lane == 0) U[r * 384 + k] = p;
        }
    }
}

// single 1024-thread block; wave-shuffle scan
__global__ void scan_kernel(int* __restrict__ counts_cursor, int* __restrict__ row_ptr, int N) {
    __shared__ int s_wsum[16];
    __shared__ int s_carry;
    int t = threadIdx.x;
    int lane = t & 63, wid = t >> 6;
    if (t == 0) { s_carry = 0; row_ptr[0] = 0; }
    __syncthreads();
    for (int start = 0; start < N; start += 1024) {
        int i = start + t;
        int v = (i < N) ? counts_cursor[i] : 0;
        int s = v;
        #pragma unroll
        for (int d = 1; d < 64; d <<= 1) {
            int u = __shfl_up(s, d);
            if (lane >= d) s += u;
        }
        if (lane == 63) s_wsum[wid] = s;
        __syncthreads();
        if (wid == 0) {
            int w = (lane < 16) ? s_wsum[lane] : 0;
            #pragma unroll
            for (int d = 1; d < 16; d <<= 1) {
                int u = __shfl_up(w, d);
                if (lane >= d) w += u;
            }
            if (lane < 16) s_wsum[lane] = w;
        }
        __syncthreads();
        int incl = s + (wid ? s_wsum[wid - 1] : 0) + s_carry;
        if (i < N) { row_ptr[i + 1] = incl; counts_cursor[i] = incl - v; }
        __syncthreads();
        if (t == 0) s_carry += s_wsum[15];
        __syncthreads();
    }
}

__global__ void fill_kernel(const int* __restrict__ ei, int E, int N,
                            int* __restrict__ cursor, int* __restrict__ col) {
    int i = blockIdx.x * blockDim.x + threadIdx.x;
    int Et = E + N;
    if (i >= Et) return;
    int s, d;
    if (i < E) { s = ei[i]; d = ei[E + i]; } else { s = d = i - E; }
    int pos = atomicAdd(&cursor[d], 1);
    col[pos] = s;
}

// ---------------- logits via U: ss1[n][h]=x[n]·U[h], sd1[n][h]=x[n]·U[4+h] ----------------
__global__ void sU_kernel(const unsigned short* __restrict__ xb, const float* __restrict__ U,
                          float* __restrict__ ss1, float* __restrict__ sd1, int N) {
    int wid = (blockIdx.x * blockDim.x + threadIdx.x) >> 6;
    int lane = threadIdx.x & 63;
    if (wid >= N) return;
    int half = lane >> 5, l32 = lane & 31;
    int c0 = l32 * 12;
    const unsigned short* row = xb + (size_t)wid * 384 + c0;
    ushortx8 v8 = *(const ushortx8*)row;
    ushortx4 v4 = *(const ushortx4*)(row + 8);
    float xv[12];
    #pragma unroll
    for (int j = 0; j < 8; j++) xv[j] = bf2f(v8[j]);
    #pragma unroll
    for (int j = 0; j < 4; j++) xv[8 + j] = bf2f(v4[j]);
    float p[4];
    #pragma unroll
    for (int r = 0; r < 4; r++) {
        const float* u = U + (half * 4 + r) * 384 + c0;
        float s = 0.f;
        #pragma unroll
        for (int j = 0; j < 12; j++) s += xv[j] * u[j];
        #pragma unroll
        for (int off = 16; off; off >>= 1) s += __shfl_xor(s, off);
        p[r] = s;
    }
    if (l32 == 0) {
        float* dst = half ? (sd1 + wid * 4) : (ss1 + wid * 4);
        dst[0] = p[0]; dst[1] = p[1]; dst[2] = p[2]; dst[3] = p[3];
    }
}

// ---------------- per-node attention logits, layer 2 (H=1, C=256), bf16 h2 ----------------
__global__ void s2_kernel(const unsigned short* __restrict__ h2b, const float* __restrict__ a_src,
                          const float* __restrict__ a_dst, float* __restrict__ ssrc,
                          float* __restrict__ sdst, int N) {
    int wid = (blockIdx.x * blockDim.x + threadIdx.x) >> 6;
    int lane = threadIdx.x & 63;
    if (wid >= N) return;
    ushortx4 v = *(const ushortx4*)(h2b + (size_t)wid * 256 + lane * 4);
    float4 a = ((const float4*)a_src)[lane];
    float4 d = ((const float4*)a_dst)[lane];
    float v0 = bf2f(v[0]), v1 = bf2f(v[1]), v2 = bf2f(v[2]), v3 = bf2f(v[3]);
    float s = v0 * a.x + v1 * a.y + v2 * a.z + v3 * a.w;
    float t = v0 * d.x + v1 * d.y + v2 * d.z + v3 * d.w;
    for (int off = 32; off; off >>= 1) { s += __shfl_xor(s, off); t += __shfl_xor(t, off); }
    if (lane == 0) { ssrc[wid] = s; sdst[wid] = t; }
}

// ---------------- per-edge softmax weights, layer 1 (H=4) ----------------
__global__ __launch_bounds__(256) void alpha1_kernel(const float* __restrict__ ssrc,
        const float* __restrict__ sdst, const int* __restrict__ row_ptr,
        const int* __restrict__ col, float* __restrict__ wx, float* __restrict__ den, int N) {
    int wid = (blockIdx.x * blockDim.x + threadIdx.x) >> 6;
    int lane = threadIdx.x & 63;
    if (wid >= N) return;
    int base = row_ptr[wid];
    int deg = row_ptr[wid + 1] - base;
    float sd0 = sdst[wid * 4 + 0], sd1 = sdst[wid * 4 + 1];
    float sd2 = sdst[wid * 4 + 2], sd3 = sdst[wid * 4 + 3];
    float m0 = -1e30f, m1 = -1e30f, m2 = -1e30f, m3 = -1e30f;
    for (int i = lane; i < deg; i += 64) {
        int s = col[base + i];
        const float* sp = ssrc + s * 4;
        m0 = fmaxf(m0, lrelu(sp[0] + sd0));
        m1 = fmaxf(m1, lrelu(sp[1] + sd1));
        m2 = fmaxf(m2, lrelu(sp[2] + sd2));
        m3 = fmaxf(m3, lrelu(sp[3] + sd3));
    }
    #pragma unroll
    for (int off = 32; off; off >>= 1) {
        m0 = fmaxf(m0, __shfl_xor(m0, off));
        m1 = fmaxf(m1, __shfl_xor(m1, off));
        m2 = fmaxf(m2, __shfl_xor(m2, off));
        m3 = fmaxf(m3, __shfl_xor(m3, off));
    }
    float d0 = 0.f, d1 = 0.f, d2 = 0.f, d3 = 0.f;
    for (int i = lane; i < deg; i += 64) {
        int s = col[base + i];
        const float* sp = ssrc + s * 4;
        float4 w4;
        w4.x = __expf(lrelu(sp[0] + sd0) - m0); d0 += w4.x;
        w4.y = __expf(lrelu(sp[1] + sd1) - m1); d1 += w4.y;
        w4.z = __expf(lrelu(sp[2] + sd2) - m2); d2 += w4.z;
        w4.w = __expf(lrelu(sp[3] + sd3) - m3); d3 += w4.w;
        *(float4*)(wx + (size_t)(base + i) * 4) = w4;
    }
    #pragma unroll
    for (int off = 32; off; off >>= 1) {
        d0 += __shfl_xor(d0, off);
        d1 += __shfl_xor(d1, off);
        d2 += __shfl_xor(d2, off);
        d3 += __shfl_xor(d3, off);
    }
    if (lane == 0) {
        den[wid * 4 + 0] = d0; den[wid * 4 + 1] = d1;
        den[wid * 4 + 2] = d2; den[wid * 4 + 3] = d3;
    }
}

// ---------------- per-edge softmax weights, layer 2 (H=1) ----------------
__global__ __launch_bounds__(256) void alpha2_kernel(const float* __restrict__ ssrc,
        const float* __restrict__ sdst, const int* __restrict__ row_ptr,
        const int* __restrict__ col, float* __restrict__ wx, float* __restrict__ den, int N) {
    int wid = (blockIdx.x * blockDim.x + threadIdx.x) >> 6;
    int lane = threadIdx.x & 63;
    if (wid >= N) return;
    int base = row_ptr[wid];
    int deg = row_ptr[wid + 1] - base;
    float sd = sdst[wid];
    float m = -1e30f;
    for (int i = lane; i < deg; i += 64) {
        int s = col[base + i];
        m = fmaxf(m, lrelu(ssrc[s] + sd));
    }
    #pragma unroll
    for (int off = 32; off; off >>= 1) m = fmaxf(m, __shfl_xor(m, off));
    float d = 0.f;
    for (int i = lane; i < deg; i += 64) {
        int s = col[base + i];
        float x = __expf(lrelu(ssrc[s] + sd) - m);
        d += x;
        wx[base + i] = x;
    }
    #pragma unroll
    for (int off = 32; off; off >>= 1) d += __shfl_xor(d, off);
    if (lane == 0) den[wid] = d;
}

// ---------------- aggx: per-head weighted aggregation of x rows (384 ch) ----------------
// NOTE: epilogue must NOT index acc[] with a runtime value — scratch demotion (r7/r8).
__global__ __launch_bounds__(256) void aggx_kernel(const unsigned short* __restrict__ xb,
        const float* __restrict__ wx, const float* __restrict__ den,
        const int* __restrict__ row_ptr, const int* __restrict__ col,
        unsigned short* __restrict__ aggxn, int N) {
    __shared__ unsigned short lds[4][1536];
    int t = threadIdx.x;
    int wv = t >> 6;
    int wid = blockIdx.x * 4 + wv;
    int lane = t & 63;
    bool active = wid < N;
    int half = lane >> 5, l32 = lane & 31;
    int c0 = l32 * 12;
    if (active) {
        int base = row_ptr[wid];
        int deg = row_ptr[wid + 1] - base;
        float acc[4][12] = {};
        for (int i = half; i < deg; i += 2) {
            int e = base + i;
            int s = col[e];
            float4 w4 = *(const float4*)(wx + (size_t)e * 4);
            const unsigned short* row = xb + (size_t)s * 384 + c0;
            ushortx8 v8 = *(const ushortx8*)row;
            ushortx4 v4 = *(const ushortx4*)(row + 8);
            float xv[12];
            #pragma unroll
            for (int j = 0; j < 8; j++) xv[j] = bf2f(v8[j]);
            #pragma unroll
            for (int j = 0; j < 4; j++) xv[8 + j] = bf2f(v4[j]);
            #pragma unroll
            for (int j = 0; j < 12; j++) {
                acc[0][j] += w4.x * xv[j];
                acc[1][j] += w4.y * xv[j];
                acc[2][j] += w4.z * xv[j];
                acc[3][j] += w4.w * xv[j];
            }
        }
        #pragma unroll
        for (int h = 0; h < 4; h++)
            #pragma unroll
            for (int j = 0; j < 12; j++)
                acc[h][j] += __shfl_xor(acc[h][j], 32);
        #pragma unroll
        for (int hh = 0; hh < 2; hh++) {
            int h = half * 2 + hh;   // runtime — used for LDS addressing / den only
            float inv = 1.f / (den[wid * 4 + h] + 1e-16f);
            ushortx8 o8; ushortx4 o4;
            #pragma unroll
            for (int j = 0; j < 8; j++) {
                float v = half ? acc[2 + hh][j] : acc[hh][j];
                o8[j] = f2bf(v * inv);
            }
            #pragma unroll
            for (int j = 0; j < 4; j++) {
                float v = half ? acc[2 + hh][8 + j] : acc[hh][8 + j];
                o4[j] = f2bf(v * inv);
            }
            unsigned short* lp = &lds[wv][h * 384 + c0];
            *(ushortx8*)lp = o8;
            *(ushortx4*)(lp + 8) = o4;
        }
    }
    __syncthreads();
    size_t blockBase = (size_t)blockIdx.x * 4 * 1536;
    const unsigned short* lflat = &lds[0][0];
    #pragma unroll
    for (int j = 0; j < 3; j++) {
        int so = j * 2048 + t * 8;
        int node = blockIdx.x * 4 + so / 1536;
        if (node < N)
            *(ushortx8*)(aggxn + blockBase + so) = *(const ushortx8*)(lflat + so);
    }
}

#define LDK 40  // 32 + 8 pad (shorts) -> 80 B row stride, 2-way (free) frag-read conflicts

// ---------------- layer-1 head-GEMM: h1e = elu(aggxn_head @ w1t_cols + b1), bf16 out ----------------
__global__ __launch_bounds__(256) void gemm_l1(const unsigned short* __restrict__ A,
        const unsigned short* __restrict__ Bt, const float* __restrict__ bias,
        unsigned short* __restrict__ Cout, int M) {
    __shared__ unsigned short As[128 * LDK];
    __shared__ unsigned short Bs[128 * LDK];
    int t = threadIdx.x;
    int lane = t & 63, wave = t >> 6;
    int wm = (wave >> 1) * 64, wn = (wave & 1) * 64;
    int q = lane >> 4, l16 = lane & 15;
    int row0 = blockIdx.y * 128, col0 = blockIdx.x * 128;
    int hoff = (col0 >> 8) * 384;
    floatx4 acc[4][4] = {};
    int sg = (t & 7) * 4;
    int sr = t >> 3;
    for (int kt = 0; kt < 384; kt += 32) {
        #pragma unroll
        for (int p = 0; p < 4; p++) {
            int r = sr + p * 32;
            int ga = min(row0 + r, M - 1);
            *(ushortx4*)&As[r * LDK + sg] = *(const ushortx4*)(A + (size_t)ga * 1536 + hoff + kt + sg);
        }
        #pragma unroll
        for (int p = 0; p < 4; p++) {
            int r = sr + p * 32;
            *(ushortx4*)&Bs[r * LDK + sg] = *(const ushortx4*)(Bt + (size_t)(col0 + r) * 384 + kt + sg);
        }
        __syncthreads();
        bf16x8 af[4], bfr[4];
        #pragma unroll
        for (int i = 0; i < 4; i++)
            af[i] = *(const bf16x8*)&As[(wm + i * 16 + l16) * LDK + q * 8];
        #pragma unroll
        for (int j = 0; j < 4; j++)
            bfr[j] = *(const bf16x8*)&Bs[(wn + j * 16 + l16) * LDK + q * 8];
        #pragma unroll
        for (int i = 0; i < 4; i++)
            #pragma unroll
            for (int j = 0; j < 4; j++)
                acc[i][j] = __builtin_amdgcn_mfma_f32_16x16x32_bf16(af[i], bfr[j], acc[i][j], 0, 0, 0);
        __syncthreads();
    }
    float bj[4];
    #pragma unroll
    for (int j = 0; j < 4; j++) bj[j] = bias[col0 + wn + l16 + j * 16];
    #pragma unroll
    for (int i = 0; i < 4; i++) {
        #pragma unroll
        for (int r = 0; r < 4; r++) {
            int grow = row0 + wm + i * 16 + q * 4 + r;
            if (grow < M) {
                unsigned short* cp = Cout + (size_t)grow * 1024 + col0 + wn + l16;
                #pragma unroll
                for (int j = 0; j < 4; j++) cp[j * 16] = f2bf(eluf(acc[i][j][r] + bj[j]));
            }
        }
    }
}

// ---------------- bf16 MFMA GEMM (layer 2): C = A @ Bt^T, bf16 out ----------------
template <int TN>
__global__ __launch_bounds__(256) void gemm_1t(const unsigned short* __restrict__ A,
        const unsigned short* __restrict__ Bt, unsigned short* __restrict__ Cout,
        int M, int N, int K) {
    constexpr int JN = TN / 32;
    __shared__ unsigned short As[128 * LDK];
    __shared__ unsigned short Bs[TN * LDK];
    int t = threadIdx.x;
    int lane = t & 63, wave = t >> 6;
    int wm = (wave >> 1) * 64, wn = (wave & 1) * (TN / 2);
    int q = lane >> 4, l16 = lane & 15;
    int row0 = blockIdx.y * 128, col0 = blockIdx.x * TN;
    floatx4 acc[4][JN] = {};
    int sg = (t & 7) * 4;
    int sr = t >> 3;
    for (int kt = 0; kt < K; kt += 32) {
        #pragma unroll
        for (int p = 0; p < 4; p++) {
            int r = sr + p * 32;
            int ga = min(row0 + r, M - 1);
            *(ushortx4*)&As[r * LDK + sg] = *(const ushortx4*)(A + (size_t)ga * K + kt + sg);
        }
        #pragma unroll
        for (int p = 0; p < TN / 32; p++) {
            int r = sr + p * 32;
            *(ushortx4*)&Bs[r * LDK + sg] = *(const ushortx4*)(Bt + (size_t)(col0 + r) * K + kt + sg);
        }
        __syncthreads();
        bf16x8 af[4], bfr[JN];
        #pragma unroll
        for (int i = 0; i < 4; i++)
            af[i] = *(const bf16x8*)&As[(wm + i * 16 + l16) * LDK + q * 8];
        #pragma unroll
        for (int j = 0; j < JN; j++)
            bfr[j] = *(const bf16x8*)&Bs[(wn + j * 16 + l16) * LDK + q * 8];
        #pragma unroll
        for (int i = 0; i < 4; i++)
            #pragma unroll
            for (int j = 0; j < JN; j++)
                acc[i][j] = __builtin_amdgcn_mfma_f32_16x16x32_bf16(af[i], bfr[j], acc[i][j], 0, 0, 0);
        __syncthreads();
    }
    #pragma unroll
    for (int i = 0; i < 4; i++) {
        #pragma unroll
        for (int r = 0; r < 4; r++) {
            int grow = row0 + wm + i * 16 + q * 4 + r;
            if (grow < M) {
                unsigned short* cp = Cout + (size_t)grow * N + col0 + wn + l16;
                #pragma unroll
                for (int j = 0; j < JN; j++) cp[j * 16] = f2bf(acc[i][j][r]);
            }
        }
    }
}

// ---------------- layer-2 aggregation: gather+FMA; fp32 out + bf16 shadow ----------------
__global__ __launch_bounds__(256) void agg2_kernel(const unsigned short* __restrict__ h2b,
        const float* __restrict__ wx, const float* __restrict__ den,
        const int* __restrict__ row_ptr, const int* __restrict__ col,
        const float* __restrict__ bias, float* __restrict__ out,
        unsigned short* __restrict__ outb, int N) {
    int wid = (blockIdx.x * blockDim.x + threadIdx.x) >> 6;
    int lane = threadIdx.x & 63;
    if (wid >= N) return;
    int base = row_ptr[wid];
    int deg = row_ptr[wid + 1] - base;
    float4 a = {0, 0, 0, 0};
    int c = lane * 4;
    int i = 0;
    for (; i + 1 < deg; i += 2) {
        int s0 = col[base + i], s1 = col[base + i + 1];
        float x0 = wx[base + i], x1 = wx[base + i + 1];
        ushortx4 v0 = *(const ushortx4*)(h2b + (size_t)s0 * 256 + c);
        ushortx4 v1 = *(const ushortx4*)(h2b + (size_t)s1 * 256 + c);
        a.x += x0 * bf2f(v0[0]) + x1 * bf2f(v1[0]);
        a.y += x0 * bf2f(v0[1]) + x1 * bf2f(v1[1]);
        a.z += x0 * bf2f(v0[2]) + x1 * bf2f(v1[2]);
        a.w += x0 * bf2f(v0[3]) + x1 * bf2f(v1[3]);
    }
    if (i < deg) {
        int s0 = col[base + i];
        float x0 = wx[base + i];
        ushortx4 v0 = *(const ushortx4*)(h2b + (size_t)s0 * 256 + c);
        a.x += x0 * bf2f(v0[0]); a.y += x0 * bf2f(v0[1]);
        a.z += x0 * bf2f(v0[2]); a.w += x0 * bf2f(v0[3]);
    }
    float inv = 1.f / (den[wid] + 1e-16f);
    float4 o;
    o.x = eluf(a.x * inv + bias[c + 0]);
    o.y = eluf(a.y * inv + bias[c + 1]);
    o.z = eluf(a.z * inv + bias[c + 2]);
    o.w = eluf(a.w * inv + bias[c + 3]);
    *(float4*)(out + (size_t)wid * 256 + c) = o;
    ushortx4 ob;
    ob[0] = f2bf(o.x); ob[1] = f2bf(o.y); ob[2] = f2bf(o.z); ob[3] = f2bf(o.w);
    *(ushortx4*)(outb + (size_t)wid * 256 + c) = ob;
}

// ---------------- merged tail: MFMA influence head (128 rows/block) | mean ----------------
// infl = sigmoid(relu(hbf @ wp1t^T + bp1) @ Wp2 + bp2)
__global__ __launch_bounds__(256) void tail_kernel(const float* __restrict__ h,
        const unsigned short* __restrict__ hbf, const unsigned short* __restrict__ wp1t,
        const float* __restrict__ bp1, const float* __restrict__ Wp2,
        const float* __restrict__ bp2, float* __restrict__ gf, float* __restrict__ infl, int M) {
    int b = blockIdx.x;
    int nInfl = (M + 127) / 128;
    if (b < nInfl) {
        __shared__ unsigned short As[128 * LDK];
        __shared__ unsigned short Bs[128 * LDK];
        __shared__ float partial[2][128];
        int t = threadIdx.x;
        int lane = t & 63, wave = t >> 6;
        int wm = (wave >> 1) * 64, wn = (wave & 1) * 64;
        int q = lane >> 4, l16 = lane & 15;
        int row0 = b * 128;
        floatx4 acc[4][4] = {};
        int sg = (t & 7) * 4;
        int sr = t >> 3;
        for (int kt = 0; kt < 256; kt += 32) {
            #pragma unroll
            for (int p = 0; p < 4; p++) {
                int r = sr + p * 32;
                int ga = min(row0 + r, M - 1);
                *(ushortx4*)&As[r * LDK + sg] = *(const ushortx4*)(hbf + (size_t)ga * 256 + kt + sg);
                *(ushortx4*)&Bs[r * LDK + sg] = *(const ushortx4*)(wp1t + (size_t)r * 256 + kt + sg);
            }
            __syncthreads();
            bf16x8 af[4], bfr[4];
            #pragma unroll
            for (int i = 0; i < 4; i++)
                af[i] = *(const bf16x8*)&As[(wm + i * 16 + l16) * LDK + q * 8];
            #pragma unroll
            for (int j = 0; j < 4; j++)
                bfr[j] = *(const bf16x8*)&Bs[(wn + j * 16 + l16) * LDK + q * 8];
            #pragma unroll
            for (int i = 0; i < 4; i++)
                #pragma unroll
                for (int j = 0; j < 4; j++)
                    acc[i][j] = __builtin_amdgcn_mfma_f32_16x16x32_bf16(af[i], bfr[j], acc[i][j], 0, 0, 0);
            __syncthreads();
        }
        // epilogue: per-row reduce relu(acc + bp1[col]) * Wp2[col] over this wave's 64 cols
        float b1v[4], w2v[4];
        #pragma unroll
        for (int j = 0; j < 4; j++) {
            int colj = wn + j * 16 + l16;
            b1v[j] = bp1[colj];
            w2v[j] = Wp2[colj];
        }
        #pragma unroll
        for (int i = 0; i < 4; i++) {
            #pragma unroll
            for (int r = 0; r < 4; r++) {
                float s = fmaxf(acc[i][0][r] + b1v[0], 0.f) * w2v[0]
                        + fmaxf(acc[i][1][r] + b1v[1], 0.f) * w2v[1]
                        + fmaxf(acc[i][2][r] + b1v[2], 0.f) * w2v[2]
                        + fmaxf(acc[i][3][r] + b1v[3], 0.f) * w2v[3];
                #pragma unroll
                for (int off = 1; off < 16; off <<= 1) s += __shfl_xor(s, off);
                if (l16 == 0) partial[wave & 1][wm + i * 16 + q * 4 + r] = s;
            }
        }
        __syncthreads();
        if (t < 128) {
            int row = row0 + t;
            if (row < M) {
                float v = partial[0][t] + partial[1][t] + bp2[0];
                infl[row] = 1.f / (1.f + __expf(-v));
            }
        }
    } else {
        int bb = b - nInfl;            // 0..79
        int c = threadIdx.x;
        int per = (M + 79) / 80;
        int n0 = bb * per;
        int n1 = min(M, n0 + per);
        float acc = 0.f;
        for (int n = n0; n < n1; n++) acc += h[(size_t)n * 256 + c];
        atomicAdd(&gf[c], acc * (1.0f / M));
    }
}

extern "C" void kernel_launch(void* const* d_in, const int* in_sizes, int n_in,
                              void* d_out, int out_size, void* d_ws, size_t ws_size,
                              hipStream_t stream) {
    const float* x   = (const float*)d_in[0];
    const int*   ei  = (const int*)d_in[1];
    const float* W1  = (const float*)d_in[2];
    const float* as1 = (const float*)d_in[3];
    const float* ad1 = (const float*)d_in[4];
    const float* b1  = (const float*)d_in[5];
    const float* W2  = (const float*)d_in[6];
    const float* as2 = (const float*)d_in[7];
    const float* ad2 = (const float*)d_in[8];
    const float* b2  = (const float*)d_in[9];
    const float* Wp1 = (const float*)d_in[10];
    const float* bp1 = (const float*)d_in[11];
    const float* Wp2 = (const float*)d_in[12];
    const float* bp2 = (const float*)d_in[13];

    const int N  = in_sizes[0] / 384;   // 20000
    const int E  = in_sizes[1] / 2;     // 320000
    const int Et = E + N;

    // ---- workspace layout ----
    char* wsp = (char*)d_ws;
    unsigned short* xb    = (unsigned short*)wsp; wsp += (size_t)N * 384  * sizeof(short);
    unsigned short* aggxn = (unsigned short*)wsp; wsp += (size_t)N * 1536 * sizeof(short);
    unsigned short* h1eb  = (unsigned short*)wsp; wsp += (size_t)N * 1024 * sizeof(short);
    unsigned short* h2b   = (unsigned short*)wsp; wsp += (size_t)N * 256  * sizeof(short);
    unsigned short* hbf   = (unsigned short*)wsp; wsp += (size_t)N * 256  * sizeof(short);
    unsigned short* w1t   = (unsigned short*)wsp; wsp += (size_t)1024 * 384 * sizeof(short);
    unsigned short* w2t   = (unsigned short*)wsp; wsp += (size_t)256 * 1024 * sizeof(short);
    unsigned short* wp1t  = (unsigned short*)wsp; wsp += (size_t)128 * 256 * sizeof(short);
    float* U   = (float*)wsp; wsp += (size_t)8 * 384 * sizeof(float);
    float* ss1 = (float*)wsp; wsp += (size_t)N * 4 * sizeof(float);
    float* sd1 = (float*)wsp; wsp += (size_t)N * 4 * sizeof(float);
    float* ss2 = (float*)wsp; wsp += (size_t)N * sizeof(float);
    float* sd2 = (float*)wsp; wsp += (size_t)N * sizeof(float);
    float* den1 = (float*)wsp; wsp += (size_t)N * 4 * sizeof(float);
    float* den2 = (float*)wsp; wsp += (size_t)N * sizeof(float);
    float* wx1  = (float*)wsp; wsp += (size_t)Et * 4 * sizeof(float);
    float* wx2  = (float*)wsp; wsp += (size_t)Et * sizeof(float);
    int* row_ptr = (int*)wsp; wsp += (size_t)(N + 1) * sizeof(int);
    int* cursor  = (int*)wsp; wsp += (size_t)N * sizeof(int);
    int* col     = (int*)wsp;

    float* out_h  = (float*)d_out;             // [N,256]
    float* out_gf = out_h + (size_t)N * 256;   // [256]
    float* out_if = out_gf + 256;              // [N]

    // prep (count + convert + transposes + U) ; cursor must be zeroed first
    hipMemsetAsync(cursor, 0, (size_t)N * sizeof(int), stream);
    int nA = (Et + 255) / 256;
    int nB = (N * 96 + 255) / 256;
    int nPrep = nA + nB + 384 + 256 + 32 + 96;
    prep_kernel<<<nPrep, 256, 0, stream>>>(ei, E, N, cursor, x, xb, W1, w1t, W2, w2t, Wp1, wp1t, as1, ad1, U);
    scan_kernel<<<1, 1024, 0, stream>>>(cursor, row_ptr, N);
    fill_kernel<<<nA, 256, 0, stream>>>(ei, E, N, cursor, col);

    // layer 1 (h1 never materialized)
    sU_kernel<<<(N + 3) / 4, 256, 0, stream>>>(xb, U, ss1, sd1, N);
    alpha1_kernel<<<(N + 3) / 4, 256, 0, stream>>>(ss1, sd1, row_ptr, col, wx1, den1, N);
    aggx_kernel<<<(N + 3) / 4, 256, 0, stream>>>(xb, wx1, den1, row_ptr, col, aggxn, N);
    gemm_l1<<<dim3(8, (N + 127) / 128), 256, 0, stream>>>(aggxn, w1t, b1, h1eb, N);

    // layer 2
    gemm_1t<64><<<dim3(4, (N + 127) / 128), 256, 0, stream>>>(h1eb, w2t, h2b, N, 256, 1024);
    s2_kernel<<<(N + 3) / 4, 256, 0, stream>>>(h2b, as2, ad2, ss2, sd2, N);
    alpha2_kernel<<<(N + 3) / 4, 256, 0, stream>>>(ss2, sd2, row_ptr, col, wx2, den2, N);
    agg2_kernel<<<(N + 3) / 4, 256, 0, stream>>>(h2b, wx2, den2, row_ptr, col, b2, out_h, hbf, N);

    // outputs 2 & 3 (merged: MFMA influence head + mean)
    hipMemsetAsync(out_gf, 0, 256 * sizeof(float), stream);
    tail_kernel<<<(N + 127) / 128 + 80, 256, 0, stream>>>(out_h, hbf, wp1t, bp1, Wp2, bp2, out_gf, out_if, N);
}

// Round 11
// 378.014 us; speedup vs baseline: 1.4131x; 1.1200x over previous
//
#include <hip/hip_runtime.h>

#define NEG_SLOPE 0.2f

typedef __bf16 bf16x8 __attribute__((ext_vector_type(8)));
typedef float floatx4 __attribute__((ext_vector_type(4)));
typedef unsigned short ushortx4 __attribute__((ext_vector_type(4)));
typedef unsigned short ushortx8 __attribute__((ext_vector_type(8)));

__device__ __forceinline__ float eluf(float x) { return x > 0.f ? x : __expf(x) - 1.f; }
__device__ __forceinline__ float lrelu(float x) { return x > 0.f ? x : NEG_SLOPE * x; }

__device__ __forceinline__ unsigned short f2bf(float f) {
    unsigned u = __float_as_uint(f);
    u += 0x7FFFu + ((u >> 16) & 1u);           // round-to-nearest-even
    return (unsigned short)(u >> 16);
}
__device__ __forceinline__ float bf2f(unsigned short h) {
    return __uint_as_float(((unsigned)h) << 16);
}

// ========= merged prep: count | x->bf16 | W1^T | W2^T | Wp1^T | U = W1·a =========
__global__ __launch_bounds__(256) void prep_kernel(
        const int* __restrict__ ei, int E, int N, int* __restrict__ counts,
        const float* __restrict__ x, unsigned short* __restrict__ xb,
        const float* __restrict__ W1, unsigned short* __restrict__ w1t,
        const float* __restrict__ W2, unsigned short* __restrict__ w2t,
        const float* __restrict__ Wp1, unsigned short* __restrict__ wp1t,
        const float* __restrict__ as1, const float* __restrict__ ad1, float* __restrict__ U) {
    __shared__ float tile[32][33];
    int b = blockIdx.x;
    int t = threadIdx.x;
    int Et = E + N;
    int nA = (Et + 255) >> 8;
    int nB = (N * 96 + 255) >> 8;           // N*384/4 float4 groups
    if (b < nA) {
        int i = b * 256 + t;
        if (i < Et) {
            int d = (i < E) ? ei[E + i] : (i - E);
            atomicAdd(&counts[d], 1);
        }
    } else if (b < nA + nB) {
        int i = (b - nA) * 256 + t;
        if (i < N * 96) {
            float4 v = ((const float4*)x)[i];
            ushortx4 o;
            o[0] = f2bf(v.x); o[1] = f2bf(v.y); o[2] = f2bf(v.z); o[3] = f2bf(v.w);
            *(ushortx4*)(xb + (size_t)i * 4) = o;
        }
    } else if (b < nA + nB + 384) {
        int idx = b - nA - nB;
        int n0 = (idx & 31) * 32, k0 = (idx >> 5) * 32;
        int tx = t & 31, ty = t >> 5;
        #pragma unroll
        for (int i = 0; i < 32; i += 8)
            tile[ty + i][tx] = W1[(size_t)(k0 + ty + i) * 1024 + n0 + tx];
        __syncthreads();
        #pragma unroll
        for (int i = 0; i < 32; i += 8)
            w1t[(size_t)(n0 + ty + i) * 384 + k0 + tx] = f2bf(tile[tx][ty + i]);
    } else if (b < nA + nB + 384 + 256) {
        int idx = b - nA - nB - 384;
        int n0 = (idx & 7) * 32, k0 = (idx >> 3) * 32;
        int tx = t & 31, ty = t >> 5;
        #pragma unroll
        for (int i = 0; i < 32; i += 8)
            tile[ty + i][tx] = W2[(size_t)(k0 + ty + i) * 256 + n0 + tx];
        __syncthreads();
        #pragma unroll
        for (int i = 0; i < 32; i += 8)
            w2t[(size_t)(n0 + ty + i) * 1024 + k0 + tx] = f2bf(tile[tx][ty + i]);
    } else if (b < nA + nB + 384 + 256 + 32) {
        // Wp1 [256][128] -> wp1t [128][256] bf16
        int idx = b - nA - nB - 384 - 256;
        int n0 = (idx & 3) * 32, k0 = (idx >> 2) * 32;
        int tx = t & 31, ty = t >> 5;
        #pragma unroll
        for (int i = 0; i < 32; i += 8)
            tile[ty + i][tx] = Wp1[(size_t)(k0 + ty + i) * 128 + n0 + tx];
        __syncthreads();
        #pragma unroll
        for (int i = 0; i < 32; i += 8)
            wp1t[(size_t)(n0 + ty + i) * 256 + k0 + tx] = f2bf(tile[tx][ty + i]);
    } else {
        // U[8][384]: U[r][k] = sum_c W1[k][h*256+c] * a[h][c], h=r&3, a = src(r<4)/dst
        int idx = b - nA - nB - 384 - 256 - 32;
        int k = idx * 4 + (t >> 6);
        int lane = t & 63;
        #pragma unroll
        for (int r = 0; r < 8; r++) {
            int h = r & 3;
            const float* a = (r < 4 ? as1 : ad1) + h * 256 + lane * 4;
            const float* w = W1 + (size_t)k * 1024 + h * 256 + lane * 4;
            float4 wv = *(const float4*)w;
            float4 av = *(const float4*)a;
            float p = wv.x * av.x + wv.y * av.y + wv.z * av.z + wv.w * av.w;
            #pragma unroll
            for (int off = 32; off; off >>= 1) p += __shfl_xor(p, off);
            if (lane == 0) U[r * 384 + k] = p;
        }
    }
}

// single 1024-thread block; wave-shuffle scan
__global__ void scan_kernel(int* __restrict__ counts_cursor, int* __restrict__ row_ptr, int N) {
    __shared__ int s_wsum[16];
    __shared__ int s_carry;
    int t = threadIdx.x;
    int lane = t & 63, wid = t >> 6;
    if (t == 0) { s_carry = 0; row_ptr[0] = 0; }
    __syncthreads();
    for (int start = 0; start < N; start += 1024) {
        int i = start + t;
        int v = (i < N) ? counts_cursor[i] : 0;
        int s = v;
        #pragma unroll
        for (int d = 1; d < 64; d <<= 1) {
            int u = __shfl_up(s, d);
            if (lane >= d) s += u;
        }
        if (lane == 63) s_wsum[wid] = s;
        __syncthreads();
        if (wid == 0) {
            int w = (lane < 16) ? s_wsum[lane] : 0;
            #pragma unroll
            for (int d = 1; d < 16; d <<= 1) {
                int u = __shfl_up(w, d);
                if (lane >= d) w += u;
            }
            if (lane < 16) s_wsum[lane] = w;
        }
        __syncthreads();
        int incl = s + (wid ? s_wsum[wid - 1] : 0) + s_carry;
        if (i < N) { row_ptr[i + 1] = incl; counts_cursor[i] = incl - v; }
        __syncthreads();
        if (t == 0) s_carry += s_wsum[15];
        __syncthreads();
    }
}

__global__ void fill_kernel(const int* __restrict__ ei, int E, int N,
                            int* __restrict__ cursor, int* __restrict__ col) {
    int i = blockIdx.x * blockDim.x + threadIdx.x;
    int Et = E + N;
    if (i >= Et) return;
    int s, d;
    if (i < E) { s = ei[i]; d = ei[E + i]; } else { s = d = i - E; }
    int pos = atomicAdd(&cursor[d], 1);
    col[pos] = s;
}

// ---------------- logits via U: ss1[n][h]=x[n]·U[h], sd1[n][h]=x[n]·U[4+h] ----------------
__global__ void sU_kernel(const unsigned short* __restrict__ xb, const float* __restrict__ U,
                          float* __restrict__ ss1, float* __restrict__ sd1, int N) {
    int wid = (blockIdx.x * blockDim.x + threadIdx.x) >> 6;
    int lane = threadIdx.x & 63;
    if (wid >= N) return;
    int half = lane >> 5, l32 = lane & 31;
    int c0 = l32 * 12;
    const unsigned short* row = xb + (size_t)wid * 384 + c0;
    ushortx8 v8 = *(const ushortx8*)row;
    ushortx4 v4 = *(const ushortx4*)(row + 8);
    float xv[12];
    #pragma unroll
    for (int j = 0; j < 8; j++) xv[j] = bf2f(v8[j]);
    #pragma unroll
    for (int j = 0; j < 4; j++) xv[8 + j] = bf2f(v4[j]);
    float p[4];
    #pragma unroll
    for (int r = 0; r < 4; r++) {
        const float* u = U + (half * 4 + r) * 384 + c0;
        float s = 0.f;
        #pragma unroll
        for (int j = 0; j < 12; j++) s += xv[j] * u[j];
        #pragma unroll
        for (int off = 16; off; off >>= 1) s += __shfl_xor(s, off);
        p[r] = s;
    }
    if (l32 == 0) {
        float* dst = half ? (sd1 + wid * 4) : (ss1 + wid * 4);
        dst[0] = p[0]; dst[1] = p[1]; dst[2] = p[2]; dst[3] = p[3];
    }
}

// ---------------- per-node attention logits, layer 2 (H=1, C=256), bf16 h2 ----------------
__global__ void s2_kernel(const unsigned short* __restrict__ h2b, const float* __restrict__ a_src,
                          const float* __restrict__ a_dst, float* __restrict__ ssrc,
                          float* __restrict__ sdst, int N) {
    int wid = (blockIdx.x * blockDim.x + threadIdx.x) >> 6;
    int lane = threadIdx.x & 63;
    if (wid >= N) return;
    ushortx4 v = *(const ushortx4*)(h2b + (size_t)wid * 256 + lane * 4);
    float4 a = ((const float4*)a_src)[lane];
    float4 d = ((const float4*)a_dst)[lane];
    float v0 = bf2f(v[0]), v1 = bf2f(v[1]), v2 = bf2f(v[2]), v3 = bf2f(v[3]);
    float s = v0 * a.x + v1 * a.y + v2 * a.z + v3 * a.w;
    float t = v0 * d.x + v1 * d.y + v2 * d.z + v3 * d.w;
    for (int off = 32; off; off >>= 1) { s += __shfl_xor(s, off); t += __shfl_xor(t, off); }
    if (lane == 0) { ssrc[wid] = s; sdst[wid] = t; }
}

// ---------------- per-edge softmax weights, layer 1 (H=4) ----------------
__global__ __launch_bounds__(256) void alpha1_kernel(const float* __restrict__ ssrc,
        const float* __restrict__ sdst, const int* __restrict__ row_ptr,
        const int* __restrict__ col, float* __restrict__ wx, float* __restrict__ den, int N) {
    int wid = (blockIdx.x * blockDim.x + threadIdx.x) >> 6;
    int lane = threadIdx.x & 63;
    if (wid >= N) return;
    int base = row_ptr[wid];
    int deg = row_ptr[wid + 1] - base;
    float sd0 = sdst[wid * 4 + 0], sd1 = sdst[wid * 4 + 1];
    float sd2 = sdst[wid * 4 + 2], sd3 = sdst[wid * 4 + 3];
    float m0 = -1e30f, m1 = -1e30f, m2 = -1e30f, m3 = -1e30f;
    for (int i = lane; i < deg; i += 64) {
        int s = col[base + i];
        const float* sp = ssrc + s * 4;
        m0 = fmaxf(m0, lrelu(sp[0] + sd0));
        m1 = fmaxf(m1, lrelu(sp[1] + sd1));
        m2 = fmaxf(m2, lrelu(sp[2] + sd2));
        m3 = fmaxf(m3, lrelu(sp[3] + sd3));
    }
    #pragma unroll
    for (int off = 32; off; off >>= 1) {
        m0 = fmaxf(m0, __shfl_xor(m0, off));
        m1 = fmaxf(m1, __shfl_xor(m1, off));
        m2 = fmaxf(m2, __shfl_xor(m2, off));
        m3 = fmaxf(m3, __shfl_xor(m3, off));
    }
    float d0 = 0.f, d1 = 0.f, d2 = 0.f, d3 = 0.f;
    for (int i = lane; i < deg; i += 64) {
        int s = col[base + i];
        const float* sp = ssrc + s * 4;
        float4 w4;
        w4.x = __expf(lrelu(sp[0] + sd0) - m0); d0 += w4.x;
        w4.y = __expf(lrelu(sp[1] + sd1) - m1); d1 += w4.y;
        w4.z = __expf(lrelu(sp[2] + sd2) - m2); d2 += w4.z;
        w4.w = __expf(lrelu(sp[3] + sd3) - m3); d3 += w4.w;
        *(float4*)(wx + (size_t)(base + i) * 4) = w4;
    }
    #pragma unroll
    for (int off = 32; off; off >>= 1) {
        d0 += __shfl_xor(d0, off);
        d1 += __shfl_xor(d1, off);
        d2 += __shfl_xor(d2, off);
        d3 += __shfl_xor(d3, off);
    }
    if (lane == 0) {
        den[wid * 4 + 0] = d0; den[wid * 4 + 1] = d1;
        den[wid * 4 + 2] = d2; den[wid * 4 + 3] = d3;
    }
}

// ---------------- per-edge softmax weights, layer 2 (H=1) ----------------
__global__ __launch_bounds__(256) void alpha2_kernel(const float* __restrict__ ssrc,
        const float* __restrict__ sdst, const int* __restrict__ row_ptr,
        const int* __restrict__ col, float* __restrict__ wx, float* __restrict__ den, int N) {
    int wid = (blockIdx.x * blockDim.x + threadIdx.x) >> 6;
    int lane = threadIdx.x & 63;
    if (wid >= N) return;
    int base = row_ptr[wid];
    int deg = row_ptr[wid + 1] - base;
    float sd = sdst[wid];
    float m = -1e30f;
    for (int i = lane; i < deg; i += 64) {
        int s = col[base + i];
        m = fmaxf(m, lrelu(ssrc[s] + sd));
    }
    #pragma unroll
    for (int off = 32; off; off >>= 1) m = fmaxf(m, __shfl_xor(m, off));
    float d = 0.f;
    for (int i = lane; i < deg; i += 64) {
        int s = col[base + i];
        float x = __expf(lrelu(ssrc[s] + sd) - m);
        d += x;
        wx[base + i] = x;
    }
    #pragma unroll
    for (int off = 32; off; off >>= 1) d += __shfl_xor(d, off);
    if (lane == 0) den[wid] = d;
}

// ---------------- aggx: per-head weighted aggregation of x rows (384 ch) ----------------
// NOTE: epilogue must NOT index acc[] with a runtime value — scratch demotion (r7/r8).
__global__ __launch_bounds__(256) void aggx_kernel(const unsigned short* __restrict__ xb,
        const float* __restrict__ wx, const float* __restrict__ den,
        const int* __restrict__ row_ptr, const int* __restrict__ col,
        unsigned short* __restrict__ aggxn, int N) {
    __shared__ unsigned short lds[4][1536];
    int t = threadIdx.x;
    int wv = t >> 6;
    int wid = blockIdx.x * 4 + wv;
    int lane = t & 63;
    bool active = wid < N;
    int half = lane >> 5, l32 = lane & 31;
    int c0 = l32 * 12;
    if (active) {
        int base = row_ptr[wid];
        int deg = row_ptr[wid + 1] - base;
        float acc[4][12] = {};
        for (int i = half; i < deg; i += 2) {
            int e = base + i;
            int s = col[e];
            float4 w4 = *(const float4*)(wx + (size_t)e * 4);
            const unsigned short* row = xb + (size_t)s * 384 + c0;
            ushortx8 v8 = *(const ushortx8*)row;
            ushortx4 v4 = *(const ushortx4*)(row + 8);
            float xv[12];
            #pragma unroll
            for (int j = 0; j < 8; j++) xv[j] = bf2f(v8[j]);
            #pragma unroll
            for (int j = 0; j < 4; j++) xv[8 + j] = bf2f(v4[j]);
            #pragma unroll
            for (int j = 0; j < 12; j++) {
                acc[0][j] += w4.x * xv[j];
                acc[1][j] += w4.y * xv[j];
                acc[2][j] += w4.z * xv[j];
                acc[3][j] += w4.w * xv[j];
            }
        }
        #pragma unroll
        for (int h = 0; h < 4; h++)
            #pragma unroll
            for (int j = 0; j < 12; j++)
                acc[h][j] += __shfl_xor(acc[h][j], 32);
        #pragma unroll
        for (int hh = 0; hh < 2; hh++) {
            int h = half * 2 + hh;   // runtime — used for LDS addressing / den only
            float inv = 1.f / (den[wid * 4 + h] + 1e-16f);
            ushortx8 o8; ushortx4 o4;
            #pragma unroll
            for (int j = 0; j < 8; j++) {
                float v = half ? acc[2 + hh][j] : acc[hh][j];
                o8[j] = f2bf(v * inv);
            }
            #pragma unroll
            for (int j = 0; j < 4; j++) {
                float v = half ? acc[2 + hh][8 + j] : acc[hh][8 + j];
                o4[j] = f2bf(v * inv);
            }
            unsigned short* lp = &lds[wv][h * 384 + c0];
            *(ushortx8*)lp = o8;
            *(ushortx4*)(lp + 8) = o4;
        }
    }
    __syncthreads();
    size_t blockBase = (size_t)blockIdx.x * 4 * 1536;
    const unsigned short* lflat = &lds[0][0];
    #pragma unroll
    for (int j = 0; j < 3; j++) {
        int so = j * 2048 + t * 8;
        int node = blockIdx.x * 4 + so / 1536;
        if (node < N)
            *(ushortx8*)(aggxn + blockBase + so) = *(const ushortx8*)(lflat + so);
    }
}

#define LDK 40  // 32 + 8 pad (shorts) -> 80 B row stride, 2-way (free) frag-read conflicts

// ---------------- layer-1 head-GEMM: h1e = elu(aggxn_head @ w1t_cols + b1), bf16 out ----------------
__global__ __launch_bounds__(256) void gemm_l1(const unsigned short* __restrict__ A,
        const unsigned short* __restrict__ Bt, const float* __restrict__ bias,
        unsigned short* __restrict__ Cout, int M) {
    __shared__ unsigned short As[128 * LDK];
    __shared__ unsigned short Bs[128 * LDK];
    int t = threadIdx.x;
    int lane = t & 63, wave = t >> 6;
    int wm = (wave >> 1) * 64, wn = (wave & 1) * 64;
    int q = lane >> 4, l16 = lane & 15;
    int row0 = blockIdx.y * 128, col0 = blockIdx.x * 128;
    int hoff = (col0 >> 8) * 384;
    floatx4 acc[4][4] = {};
    int sg = (t & 7) * 4;
    int sr = t >> 3;
    for (int kt = 0; kt < 384; kt += 32) {
        #pragma unroll
        for (int p = 0; p < 4; p++) {
            int r = sr + p * 32;
            int ga = min(row0 + r, M - 1);
            *(ushortx4*)&As[r * LDK + sg] = *(const ushortx4*)(A + (size_t)ga * 1536 + hoff + kt + sg);
        }
        #pragma unroll
        for (int p = 0; p < 4; p++) {
            int r = sr + p * 32;
            *(ushortx4*)&Bs[r * LDK + sg] = *(const ushortx4*)(Bt + (size_t)(col0 + r) * 384 + kt + sg);
        }
        __syncthreads();
        bf16x8 af[4], bfr[4];
        #pragma unroll
        for (int i = 0; i < 4; i++)
            af[i] = *(const bf16x8*)&As[(wm + i * 16 + l16) * LDK + q * 8];
        #pragma unroll
        for (int j = 0; j < 4; j++)
            bfr[j] = *(const bf16x8*)&Bs[(wn + j * 16 + l16) * LDK + q * 8];
        #pragma unroll
        for (int i = 0; i < 4; i++)
            #pragma unroll
            for (int j = 0; j < 4; j++)
                acc[i][j] = __builtin_amdgcn_mfma_f32_16x16x32_bf16(af[i], bfr[j], acc[i][j], 0, 0, 0);
        __syncthreads();
    }
    float bj[4];
    #pragma unroll
    for (int j = 0; j < 4; j++) bj[j] = bias[col0 + wn + l16 + j * 16];
    #pragma unroll
    for (int i = 0; i < 4; i++) {
        #pragma unroll
        for (int r = 0; r < 4; r++) {
            int grow = row0 + wm + i * 16 + q * 4 + r;
            if (grow < M) {
                unsigned short* cp = Cout + (size_t)grow * 1024 + col0 + wn + l16;
                #pragma unroll
                for (int j = 0; j < 4; j++) cp[j * 16] = f2bf(eluf(acc[i][j][r] + bj[j]));
            }
        }
    }
}

// ---------------- bf16 MFMA GEMM (layer 2): C = A @ Bt^T, bf16 out ----------------
template <int TN>
__global__ __launch_bounds__(256) void gemm_1t(const unsigned short* __restrict__ A,
        const unsigned short* __restrict__ Bt, unsigned short* __restrict__ Cout,
        int M, int N, int K) {
    constexpr int JN = TN / 32;
    __shared__ unsigned short As[128 * LDK];
    __shared__ unsigned short Bs[TN * LDK];
    int t = threadIdx.x;
    int lane = t & 63, wave = t >> 6;
    int wm = (wave >> 1) * 64, wn = (wave & 1) * (TN / 2);
    int q = lane >> 4, l16 = lane & 15;
    int row0 = blockIdx.y * 128, col0 = blockIdx.x * TN;
    floatx4 acc[4][JN] = {};
    int sg = (t & 7) * 4;
    int sr = t >> 3;
    for (int kt = 0; kt < K; kt += 32) {
        #pragma unroll
        for (int p = 0; p < 4; p++) {
            int r = sr + p * 32;
            int ga = min(row0 + r, M - 1);
            *(ushortx4*)&As[r * LDK + sg] = *(const ushortx4*)(A + (size_t)ga * K + kt + sg);
        }
        #pragma unroll
        for (int p = 0; p < TN / 32; p++) {
            int r = sr + p * 32;
            *(ushortx4*)&Bs[r * LDK + sg] = *(const ushortx4*)(Bt + (size_t)(col0 + r) * K + kt + sg);
        }
        __syncthreads();
        bf16x8 af[4], bfr[JN];
        #pragma unroll
        for (int i = 0; i < 4; i++)
            af[i] = *(const bf16x8*)&As[(wm + i * 16 + l16) * LDK + q * 8];
        #pragma unroll
        for (int j = 0; j < JN; j++)
            bfr[j] = *(const bf16x8*)&Bs[(wn + j * 16 + l16) * LDK + q * 8];
        #pragma unroll
        for (int i = 0; i < 4; i++)
            #pragma unroll
            for (int j = 0; j < JN; j++)
                acc[i][j] = __builtin_amdgcn_mfma_f32_16x16x32_bf16(af[i], bfr[j], acc[i][j], 0, 0, 0);
        __syncthreads();
    }
    #pragma unroll
    for (int i = 0; i < 4; i++) {
        #pragma unroll
        for (int r = 0; r < 4; r++) {
            int grow = row0 + wm + i * 16 + q * 4 + r;
            if (grow < M) {
                unsigned short* cp = Cout + (size_t)grow * N + col0 + wn + l16;
                #pragma unroll
                for (int j = 0; j < JN; j++) cp[j * 16] = f2bf(acc[i][j][r]);
            }
        }
    }
}

// ---------------- layer-2 aggregation: gather+FMA; fp32 out + bf16 shadow ----------------
__global__ __launch_bounds__(256) void agg2_kernel(const unsigned short* __restrict__ h2b,
        const float* __restrict__ wx, const float* __restrict__ den,
        const int* __restrict__ row_ptr, const int* __restrict__ col,
        const float* __restrict__ bias, float* __restrict__ out,
        unsigned short* __restrict__ outb, int N) {
    int wid = (blockIdx.x * blockDim.x + threadIdx.x) >> 6;
    int lane = threadIdx.x & 63;
    if (wid >= N) return;
    int base = row_ptr[wid];
    int deg = row_ptr[wid + 1] - base;
    float4 a = {0, 0, 0, 0};
    int c = lane * 4;
    int i = 0;
    for (; i + 1 < deg; i += 2) {
        int s0 = col[base + i], s1 = col[base + i + 1];
        float x0 = wx[base + i], x1 = wx[base + i + 1];
        ushortx4 v0 = *(const ushortx4*)(h2b + (size_t)s0 * 256 + c);
        ushortx4 v1 = *(const ushortx4*)(h2b + (size_t)s1 * 256 + c);
        a.x += x0 * bf2f(v0[0]) + x1 * bf2f(v1[0]);
        a.y += x0 * bf2f(v0[1]) + x1 * bf2f(v1[1]);
        a.z += x0 * bf2f(v0[2]) + x1 * bf2f(v1[2]);
        a.w += x0 * bf2f(v0[3]) + x1 * bf2f(v1[3]);
    }
    if (i < deg) {
        int s0 = col[base + i];
        float x0 = wx[base + i];
        ushortx4 v0 = *(const ushortx4*)(h2b + (size_t)s0 * 256 + c);
        a.x += x0 * bf2f(v0[0]); a.y += x0 * bf2f(v0[1]);
        a.z += x0 * bf2f(v0[2]); a.w += x0 * bf2f(v0[3]);
    }
    float inv = 1.f / (den[wid] + 1e-16f);
    float4 o;
    o.x = eluf(a.x * inv + bias[c + 0]);
    o.y = eluf(a.y * inv + bias[c + 1]);
    o.z = eluf(a.z * inv + bias[c + 2]);
    o.w = eluf(a.w * inv + bias[c + 3]);
    *(float4*)(out + (size_t)wid * 256 + c) = o;
    ushortx4 ob;
    ob[0] = f2bf(o.x); ob[1] = f2bf(o.y); ob[2] = f2bf(o.z); ob[3] = f2bf(o.w);
    *(ushortx4*)(outb + (size_t)wid * 256 + c) = ob;
}

// ---------------- merged tail: MFMA influence head (128 rows/block) | mean ----------------
// infl = sigmoid(relu(hbf @ wp1t^T + bp1) @ Wp2 + bp2)
// mean branch: 160 blocks x 8 independent row-accumulators (8 loads in flight; the
// r10 version had 80 blocks x 1 acc -> ~250-deep latency chain = 52 us for a 20 MB read)
__global__ __launch_bounds__(256) void tail_kernel(const float* __restrict__ h,
        const unsigned short* __restrict__ hbf, const unsigned short* __restrict__ wp1t,
        const float* __restrict__ bp1, const float* __restrict__ Wp2,
        const float* __restrict__ bp2, float* __restrict__ gf, float* __restrict__ infl, int M) {
    int b = blockIdx.x;
    int nInfl = (M + 127) / 128;
    if (b < nInfl) {
        __shared__ unsigned short As[128 * LDK];
        __shared__ unsigned short Bs[128 * LDK];
        __shared__ float partial[2][128];
        int t = threadIdx.x;
        int lane = t & 63, wave = t >> 6;
        int wm = (wave >> 1) * 64, wn = (wave & 1) * 64;
        int q = lane >> 4, l16 = lane & 15;
        int row0 = b * 128;
        floatx4 acc[4][4] = {};
        int sg = (t & 7) * 4;
        int sr = t >> 3;
        for (int kt = 0; kt < 256; kt += 32) {
            #pragma unroll
            for (int p = 0; p < 4; p++) {
                int r = sr + p * 32;
                int ga = min(row0 + r, M - 1);
                *(ushortx4*)&As[r * LDK + sg] = *(const ushortx4*)(hbf + (size_t)ga * 256 + kt + sg);
                *(ushortx4*)&Bs[r * LDK + sg] = *(const ushortx4*)(wp1t + (size_t)r * 256 + kt + sg);
            }
            __syncthreads();
            bf16x8 af[4], bfr[4];
            #pragma unroll
            for (int i = 0; i < 4; i++)
                af[i] = *(const bf16x8*)&As[(wm + i * 16 + l16) * LDK + q * 8];
            #pragma unroll
            for (int j = 0; j < 4; j++)
                bfr[j] = *(const bf16x8*)&Bs[(wn + j * 16 + l16) * LDK + q * 8];
            #pragma unroll
            for (int i = 0; i < 4; i++)
                #pragma unroll
                for (int j = 0; j < 4; j++)
                    acc[i][j] = __builtin_amdgcn_mfma_f32_16x16x32_bf16(af[i], bfr[j], acc[i][j], 0, 0, 0);
            __syncthreads();
        }
        // epilogue: per-row reduce relu(acc + bp1[col]) * Wp2[col] over this wave's 64 cols
        float b1v[4], w2v[4];
        #pragma unroll
        for (int j = 0; j < 4; j++) {
            int colj = wn + j * 16 + l16;
            b1v[j] = bp1[colj];
            w2v[j] = Wp2[colj];
        }
        #pragma unroll
        for (int i = 0; i < 4; i++) {
            #pragma unroll
            for (int r = 0; r < 4; r++) {
                float s = fmaxf(acc[i][0][r] + b1v[0], 0.f) * w2v[0]
                        + fmaxf(acc[i][1][r] + b1v[1], 0.f) * w2v[1]
                        + fmaxf(acc[i][2][r] + b1v[2], 0.f) * w2v[2]
                        + fmaxf(acc[i][3][r] + b1v[3], 0.f) * w2v[3];
                #pragma unroll
                for (int off = 1; off < 16; off <<= 1) s += __shfl_xor(s, off);
                if (l16 == 0) partial[wave & 1][wm + i * 16 + q * 4 + r] = s;
            }
        }
        __syncthreads();
        if (t < 128) {
            int row = row0 + t;
            if (row < M) {
                float v = partial[0][t] + partial[1][t] + bp2[0];
                infl[row] = 1.f / (1.f + __expf(-v));
            }
        }
    } else {
        int bb = b - nInfl;            // 0..159
        int c = threadIdx.x;
        int per = (M + 159) / 160;
        int n0 = bb * per;
        int n1 = min(M, n0 + per);
        float a0 = 0.f, a1 = 0.f, a2 = 0.f, a3 = 0.f;
        float a4 = 0.f, a5 = 0.f, a6 = 0.f, a7 = 0.f;
        int n = n0;
        for (; n + 8 <= n1; n += 8) {
            a0 += h[(size_t)(n + 0) * 256 + c];
            a1 += h[(size_t)(n + 1) * 256 + c];
            a2 += h[(size_t)(n + 2) * 256 + c];
            a3 += h[(size_t)(n + 3) * 256 + c];
            a4 += h[(size_t)(n + 4) * 256 + c];
            a5 += h[(size_t)(n + 5) * 256 + c];
            a6 += h[(size_t)(n + 6) * 256 + c];
            a7 += h[(size_t)(n + 7) * 256 + c];
        }
        for (; n < n1; n++) a0 += h[(size_t)n * 256 + c];
        float acc = ((a0 + a1) + (a2 + a3)) + ((a4 + a5) + (a6 + a7));
        atomicAdd(&gf[c], acc * (1.0f / M));
    }
}

extern "C" void kernel_launch(void* const* d_in, const int* in_sizes, int n_in,
                              void* d_out, int out_size, void* d_ws, size_t ws_size,
                              hipStream_t stream) {
    const float* x   = (const float*)d_in[0];
    const int*   ei  = (const int*)d_in[1];
    const float* W1  = (const float*)d_in[2];
    const float* as1 = (const float*)d_in[3];
    const float* ad1 = (const float*)d_in[4];
    const float* b1  = (const float*)d_in[5];
    const float* W2  = (const float*)d_in[6];
    const float* as2 = (const float*)d_in[7];
    const float* ad2 = (const float*)d_in[8];
    const float* b2  = (const float*)d_in[9];
    const float* Wp1 = (const float*)d_in[10];
    const float* bp1 = (const float*)d_in[11];
    const float* Wp2 = (const float*)d_in[12];
    const float* bp2 = (const float*)d_in[13];

    const int N  = in_sizes[0] / 384;   // 20000
    const int E  = in_sizes[1] / 2;     // 320000
    const int Et = E + N;

    // ---- workspace layout ----
    char* wsp = (char*)d_ws;
    unsigned short* xb    = (unsigned short*)wsp; wsp += (size_t)N * 384  * sizeof(short);
    unsigned short* aggxn = (unsigned short*)wsp; wsp += (size_t)N * 1536 * sizeof(short);
    unsigned short* h1eb  = (unsigned short*)wsp; wsp += (size_t)N * 1024 * sizeof(short);
    unsigned short* h2b   = (unsigned short*)wsp; wsp += (size_t)N * 256  * sizeof(short);
    unsigned short* hbf   = (unsigned short*)wsp; wsp += (size_t)N * 256  * sizeof(short);
    unsigned short* w1t   = (unsigned short*)wsp; wsp += (size_t)1024 * 384 * sizeof(short);
    unsigned short* w2t   = (unsigned short*)wsp; wsp += (size_t)256 * 1024 * sizeof(short);
    unsigned short* wp1t  = (unsigned short*)wsp; wsp += (size_t)128 * 256 * sizeof(short);
    float* U   = (float*)wsp; wsp += (size_t)8 * 384 * sizeof(float);
    float* ss1 = (float*)wsp; wsp += (size_t)N * 4 * sizeof(float);
    float* sd1 = (float*)wsp; wsp += (size_t)N * 4 * sizeof(float);
    float* ss2 = (float*)wsp; wsp += (size_t)N * sizeof(float);
    float* sd2 = (float*)wsp; wsp += (size_t)N * sizeof(float);
    float* den1 = (float*)wsp; wsp += (size_t)N * 4 * sizeof(float);
    float* den2 = (float*)wsp; wsp += (size_t)N * sizeof(float);
    float* wx1  = (float*)wsp; wsp += (size_t)Et * 4 * sizeof(float);
    float* wx2  = (float*)wsp; wsp += (size_t)Et * sizeof(float);
    int* row_ptr = (int*)wsp; wsp += (size_t)(N + 1) * sizeof(int);
    int* cursor  = (int*)wsp; wsp += (size_t)N * sizeof(int);
    int* col     = (int*)wsp;

    float* out_h  = (float*)d_out;             // [N,256]
    float* out_gf = out_h + (size_t)N * 256;   // [256]
    float* out_if = out_gf + 256;              // [N]

    // prep (count + convert + transposes + U) ; cursor must be zeroed first
    hipMemsetAsync(cursor, 0, (size_t)N * sizeof(int), stream);
    int nA = (Et + 255) / 256;
    int nB = (N * 96 + 255) / 256;
    int nPrep = nA + nB + 384 + 256 + 32 + 96;
    prep_kernel<<<nPrep, 256, 0, stream>>>(ei, E, N, cursor, x, xb, W1, w1t, W2, w2t, Wp1, wp1t, as1, ad1, U);
    scan_kernel<<<1, 1024, 0, stream>>>(cursor, row_ptr, N);
    fill_kernel<<<nA, 256, 0, stream>>>(ei, E, N, cursor, col);

    // layer 1 (h1 never materialized)
    sU_kernel<<<(N + 3) / 4, 256, 0, stream>>>(xb, U, ss1, sd1, N);
    alpha1_kernel<<<(N + 3) / 4, 256, 0, stream>>>(ss1, sd1, row_ptr, col, wx1, den1, N);
    aggx_kernel<<<(N + 3) / 4, 256, 0, stream>>>(xb, wx1, den1, row_ptr, col, aggxn, N);
    gemm_l1<<<dim3(8, (N + 127) / 128), 256, 0, stream>>>(aggxn, w1t, b1, h1eb, N);

    // layer 2
    gemm_1t<64><<<dim3(4, (N + 127) / 128), 256, 0, stream>>>(h1eb, w2t, h2b, N, 256, 1024);
    s2_kernel<<<(N + 3) / 4, 256, 0, stream>>>(h2b, as2, ad2, ss2, sd2, N);
    alpha2_kernel<<<(N + 3) / 4, 256, 0, stream>>>(ss2, sd2, row_ptr, col, wx2, den2, N);
    agg2_kernel<<<(N + 3) / 4, 256, 0, stream>>>(h2b, wx2, den2, row_ptr, col, b2, out_h, hbf, N);

    // outputs 2 & 3 (merged: MFMA influence head + mean)
    hipMemsetAsync(out_gf, 0, 256 * sizeof(float), stream);
    tail_kernel<<<(N + 127) / 128 + 160, 256, 0, stream>>>(out_h, hbf, wp1t, bp1, Wp2, bp2, out_gf, out_if, N);
}